// Round 1
// 576.814 us; speedup vs baseline: 1.4534x; 1.4534x over previous
//
#include <hip/hip_runtime.h>
#include <hip/hip_bf16.h>

#define BB 2
#define NN 4096
#define CH 64

typedef __bf16 bf16x8 __attribute__((ext_vector_type(8)));
typedef float f32x4 __attribute__((ext_vector_type(4)));

__device__ __forceinline__ float lrelu(float v) { return fmaxf(v, 0.1f * v); }
__device__ __forceinline__ float tobf(const __hip_bfloat16& h) { return __bfloat162float(h); }

// canonical f32 input region offsets (element offsets within cn)
#define PC1_C 0
#define PC2_C 24576
#define F1_C 49152
#define F2_C 573440
#define K1_C 1097728
#define K2_C 1622016
#define WT11_C 2146304
#define BT11_C 2150400
#define WT22_C 2150464
#define BT22_C 2154560
#define WPOS_C 2154624
#define BPOS_C 2154816
#define WM1_C 2154880
#define BM1_C 2158976
#define WM2_C 2159040
#define BM2_C 2163136
#define CN_TOTAL 2163200

// bubble-insert keeping DESCENDING top-8 (largest values); bd[7] = threshold.
// compile-time indices only (stays in regs)
__device__ __forceinline__ void insert8d(float bd[8], int bi[8], float nd, int ni) {
#pragma unroll
  for (int p = 0; p < 8; ++p) {
    bool c = nd > bd[p];
    float td = c ? nd : bd[p];
    int ti = c ? ni : bi[p];
    nd = c ? bd[p] : nd;
    ni = c ? bi[p] : ni;
    bd[p] = td;
    bi[p] = ti;
  }
}

// ---- dtype detector: interpret pc1's first 4096 u16 words as bf16; f32 data's
// low mantissa halves produce ~45% exponents >= 140; true bf16 N(0,1) gives ~0.
__global__ void k_detect(const unsigned short* __restrict__ pc1raw, int* __restrict__ flag) {
  int lane = threadIdx.x;  // 64
  int bad = 0;
#pragma unroll
  for (int i = 0; i < 64; ++i) {
    unsigned short u = pc1raw[lane * 64 + i];
    int e = (u >> 7) & 0xFF;
    bad += (e >= 140) ? 1 : 0;  // |v| >= 2^13 or Inf/NaN
  }
#pragma unroll
  for (int s = 32; s; s >>= 1) bad += __shfl_xor(bad, s, 64);
  if (lane == 0) *flag = (bad > 16) ? 1 : 0;  // 1 = inputs are float32
}

// ---- ingest: convert all 16 inputs to canonical f32 (exact either way) + sanitize
__global__ __launch_bounds__(256) void k_ingest(
    const void* p0, const void* p1, const void* p2, const void* p3,
    const void* p4, const void* p5, const void* p6, const void* p7,
    const void* p8, const void* p9, const void* p10, const void* p11,
    const void* p12, const void* p13, const void* p14, const void* p15,
    const int* __restrict__ flag, float* __restrict__ dst) {
  const int cum[17] = {0, 24576, 49152, 573440, 1097728, 1622016, 2146304, 2150400,
                       2150464, 2154560, 2154624, 2154816, 2154880, 2158976, 2159040,
                       2163136, 2163200};
  size_t t = (size_t)blockIdx.x * 256 + threadIdx.x;
  if (t >= (size_t)CN_TOTAL) return;
  int seg = 0;
#pragma unroll
  for (int i = 1; i < 16; ++i) seg += (t >= (size_t)cum[i]) ? 1 : 0;
  size_t local = t - (size_t)cum[seg];
  const void* ptrs[16] = {p0, p1, p2, p3, p4, p5, p6, p7, p8, p9, p10, p11, p12, p13, p14, p15};
  const void* p = ptrs[seg];
  float v;
  if (*flag) v = ((const float*)p)[local];
  else       v = tobf(((const __hip_bfloat16*)p)[local]);
  if (!(v == v) || fabsf(v) > 1e30f) v = 0.f;  // sanitize (no-op on clean data)
  dst[t] = v;
}

// ---- Wm1/Wm2 -> bf16 canonical (row-major, Wm1 at [0,4096), Wm2 at [4096,8192))
__global__ void k_prep_wm(const float* __restrict__ cn, __hip_bfloat16* __restrict__ wmb) {
  int t = blockIdx.x * 256 + threadIdx.x;  // 8192
  float v = (t < 4096) ? cn[WM1_C + t] : cn[WM2_C + (t - 4096)];
  wmb[t] = __float2bfloat16(v);
}

// ---- prep: pc [B,3,N] f32 -> float4(x,y,z,|p|^2) [2][B][N]
__global__ __launch_bounds__(256) void k_prep_xyz(const float* __restrict__ cn,
                                                  float4* __restrict__ xyzt) {
  int t = blockIdx.x * 256 + threadIdx.x;  // 2*BB*NN threads
  int n = t & (NN - 1);
  int b = (t >> 12) & 1;
  int a = t >> 13;
  const float* p = cn + (a ? PC2_C : PC1_C) + (size_t)b * 3 * NN + n;
  float x = p[0], y = p[NN], z = p[2 * NN];
  xyzt[(size_t)(a * BB + b) * NN + n] = make_float4(x, y, z, x * x + y * y + z * z);
}

// ---- prep: W_pos [64,3] + b_pos [64] -> float4 per channel
__global__ void k_prep_wpos(const float* __restrict__ cn, float4* __restrict__ wp4) {
  int c = threadIdx.x;  // 64
  wp4[c] = make_float4(cn[WPOS_C + 3 * c], cn[WPOS_C + 3 * c + 1], cn[WPOS_C + 3 * c + 2],
                       cn[BPOS_C + c]);
}

// ---- prep: knn [B,64,N] f32 -> row-normalized f32 [2][B][N][64]  (ref: x/sqrt(sum+1e-8))
__global__ __launch_bounds__(256) void k_prep_knn(const float* __restrict__ cn,
                                                  float* __restrict__ knnt) {
  int t = blockIdx.x * 256 + threadIdx.x;  // 2*BB*NN
  int n = t & (NN - 1);
  int b = (t >> 12) & 1;
  int a = t >> 13;
  const float* col = cn + (a ? K2_C : K1_C) + (size_t)b * CH * NN + n;
  float s = 0.f;
#pragma unroll
  for (int c = 0; c < CH; ++c) { float v = col[(size_t)c * NN]; s += v * v; }
  float inv = 1.0f / sqrtf(s + 1e-8f);
  float* o = knnt + ((size_t)(a * BB + b) * NN + n) * CH;
#pragma unroll
  for (int c = 0; c < CH; ++c) o[c] = col[(size_t)c * NN] * inv;
}

// ---- prep: normalized knn f32 -> bf16 rows [2][B][N][64] for MFMA candidate gen
__global__ __launch_bounds__(256) void k_prep_knnb(const float* __restrict__ knnt,
                                                   __hip_bfloat16* __restrict__ knnb) {
  int t = blockIdx.x * 256 + threadIdx.x;  // (2*BB*NN*CH)/4 threads
  float4 v = reinterpret_cast<const float4*>(knnt)[t];
  __hip_bfloat16 o4[4] = {__float2bfloat16(v.x), __float2bfloat16(v.y),
                          __float2bfloat16(v.z), __float2bfloat16(v.w)};
  *reinterpret_cast<uint2*>(knnb + 4 * (size_t)t) = *reinterpret_cast<uint2*>(o4);
}

// ---- 1x1 convs: fbuf[sel][b][n][64], sel: 0=f1a(W11,f1) 1=f2a(W22,f2) 2=f2b(W11,f2) 3=f1b(W22,f1)
__global__ __launch_bounds__(256) void k_conv(const float* __restrict__ cn,
                                              float* __restrict__ fbuf) {
  __shared__ float wl[CH * CH];  // [c][d]
  int bid = blockIdx.x;          // 4*BB*(NN/4)
  int tile = bid & (NN / 4 - 1);
  int b = (bid >> 10) & 1;
  int sel = bid >> 11;
  const float* W = cn + ((sel == 0 || sel == 2) ? WT11_C : WT22_C);
  const float* bias = cn + ((sel == 0 || sel == 2) ? BT11_C : BT22_C);
  const float* feat = cn + ((sel == 0 || sel == 3) ? F1_C : F2_C);
  int t = threadIdx.x;
#pragma unroll
  for (int i = 0; i < 16; ++i) {
    int e = t * 16 + i;  // W[d][c] row-major -> wl[c][d]
    wl[(e & 63) * 64 + (e >> 6)] = W[e];
  }
  __syncthreads();
  int p = t >> 6, d = t & 63;
  int n = tile * 4 + p;
  const float* fc = feat + (size_t)b * CH * NN + n;
  float acc = bias[d];
#pragma unroll
  for (int c = 0; c < CH; ++c) acc += wl[c * 64 + d] * fc[(size_t)c * NN];
  fbuf[((size_t)(sel * BB + b) * NN + n) * CH + d] = acc;
}

// ======================================================================
// KNN rewrite (R6): old k_knn was VALU-issue-bound (VALUBusy 76%, MfmaUtil 0,
// 735 of 838 us): f32 dot FMAs that belong on the matrix pipe + wave-divergent
// insert8 on ~every iteration. New scheme:
//   k_knng:  bf16 MFMA cosine candidate gen (16x16x32 tiles, layout proven in
//            k_mlp) + exact-f32 euclid candidate gen. Per query: 32 disjoint
//            sub-streams (8 waves x 4 lane-groups) each keep top-8 -> 256
//            candidate indices/query/phase (u16). Superset guarantee: every
//            true top-8 item is in its sub-stream's top-8; bf16 sim error
//            ~1e-3 << per-rank gap ~2.5e-2 at the sub-stream rank-8 boundary.
//   k_refine: one wave per (query, phase): f32 re-score of 256 candidates,
//            exact top-8 extraction with lexicographic (value desc, idx asc)
//            compare == jax top_k tie-breaking. Output order within the 8 is
//            irrelevant downstream (max-pool over all 16 neighbors).
// ======================================================================

// block: 512 thr = 8 waves; 16 queries/block; wave w scans db rows [w*512, w*512+512)
__global__ __launch_bounds__(512, 4) void k_knng(
    const __hip_bfloat16* __restrict__ knnb,
    const float4* __restrict__ xyzt,
    unsigned short* __restrict__ cand) {
  int bid = blockIdx.x;  // 2*BB*(NN/16) = 1024 : x(1) | b(1) | qt(8)
  int qt = bid & (NN / 16 - 1);
  int b = (bid >> 8) & 1;
  int x = bid >> 9;
  int w = threadIdx.x >> 6;
  int lane = threadIdx.x & 63;
  int lo = lane & 15, g = lane >> 4;
  int q0 = qt * 16;
  int j0 = w * (NN / 8);  // 512-row slice per wave

  float bd[8]; int bi[8];
  size_t qgw = (size_t)(x * BB + b) * NN + q0 + lo;  // this lane's query (lo)

  // ---- phase 0: cosine similarity via bf16 MFMA (maximize dot)
  {
    const __hip_bfloat16* qb = knnb + ((size_t)(x * BB + b) * NN + q0) * CH;
    const __hip_bfloat16* db = knnb + (size_t)((1 - x) * BB + b) * NN * CH;
    // B-frag (queries, resident): n=lo, k=g*8+j ; frag0 ch[0,32), frag1 ch[32,64)
    bf16x8 qf0 = *reinterpret_cast<const bf16x8*>(qb + lo * CH + g * 8);
    bf16x8 qf1 = *reinterpret_cast<const bf16x8*>(qb + lo * CH + 32 + g * 8);
#pragma unroll
    for (int k = 0; k < 8; ++k) { bd[k] = -1e30f; bi[k] = 0; }
#pragma unroll 2
    for (int t = 0; t < 32; ++t) {
      int jb = j0 + t * 16;
      // A-frag: m=lo (db row), k=g*8+j
      const __hip_bfloat16* ar = db + (size_t)(jb + lo) * CH + g * 8;
      bf16x8 a0 = *reinterpret_cast<const bf16x8*>(ar);
      bf16x8 a1 = *reinterpret_cast<const bf16x8*>(ar + 32);
      f32x4 acc = {0.f, 0.f, 0.f, 0.f};
      acc = __builtin_amdgcn_mfma_f32_16x16x32_bf16(a0, qf0, acc, 0, 0, 0);
      acc = __builtin_amdgcn_mfma_f32_16x16x32_bf16(a1, qf1, acc, 0, 0, 0);
      // D: col=lo (query), row = g*4 + r (db row within tile)
      int mb = jb + g * 4;
      float mx = fmaxf(fmaxf(acc[0], acc[1]), fmaxf(acc[2], acc[3]));
      if (mx > bd[7]) {
        if (acc[0] > bd[7]) insert8d(bd, bi, acc[0], mb);
        if (acc[1] > bd[7]) insert8d(bd, bi, acc[1], mb + 1);
        if (acc[2] > bd[7]) insert8d(bd, bi, acc[2], mb + 2);
        if (acc[3] > bd[7]) insert8d(bd, bi, acc[3], mb + 3);
      }
    }
    unsigned int pk[4];
#pragma unroll
    for (int k = 0; k < 4; ++k)
      pk[k] = (unsigned)(bi[2 * k] & 0xffff) | ((unsigned)(bi[2 * k + 1] & 0xffff) << 16);
    *reinterpret_cast<uint4*>(cand + qgw * 512 + (size_t)(w * 4 + g) * 8) =
        make_uint4(pk[0], pk[1], pk[2], pk[3]);
  }

  // ---- phase 1: euclid, exact f32. key = 2*q.p - |p|^2 (maximize) == rank of -dist
  {
    const float4 q4 = xyzt[(size_t)(x * BB + b) * NN + q0 + lo];
    const float4* dbx = xyzt + (size_t)((1 - x) * BB + b) * NN;
    float tx = 2.f * q4.x, ty = 2.f * q4.y, tz = 2.f * q4.z;
#pragma unroll
    for (int k = 0; k < 8; ++k) { bd[k] = -1e30f; bi[k] = 0; }
#pragma unroll 2
    for (int t = 0; t < 32; ++t) {
      int jb = j0 + t * 16 + g * 4;  // lane-group owns 4 rows per tile (disjoint)
      float4 p0 = dbx[jb], p1 = dbx[jb + 1], p2 = dbx[jb + 2], p3 = dbx[jb + 3];
      float v0 = fmaf(tx, p0.x, fmaf(ty, p0.y, fmaf(tz, p0.z, -p0.w)));
      float v1 = fmaf(tx, p1.x, fmaf(ty, p1.y, fmaf(tz, p1.z, -p1.w)));
      float v2 = fmaf(tx, p2.x, fmaf(ty, p2.y, fmaf(tz, p2.z, -p2.w)));
      float v3 = fmaf(tx, p3.x, fmaf(ty, p3.y, fmaf(tz, p3.z, -p3.w)));
      float mx = fmaxf(fmaxf(v0, v1), fmaxf(v2, v3));
      if (mx > bd[7]) {
        if (v0 > bd[7]) insert8d(bd, bi, v0, jb);
        if (v1 > bd[7]) insert8d(bd, bi, v1, jb + 1);
        if (v2 > bd[7]) insert8d(bd, bi, v2, jb + 2);
        if (v3 > bd[7]) insert8d(bd, bi, v3, jb + 3);
      }
    }
    unsigned int pk[4];
#pragma unroll
    for (int k = 0; k < 4; ++k)
      pk[k] = (unsigned)(bi[2 * k] & 0xffff) | ((unsigned)(bi[2 * k + 1] & 0xffff) << 16);
    *reinterpret_cast<uint4*>(cand + qgw * 512 + 256 + (size_t)(w * 4 + g) * 8) =
        make_uint4(pk[0], pk[1], pk[2], pk[3]);
  }
}

// ---- refine: one wave per (query, phase). 256 candidates -> exact f32 top-8.
__global__ __launch_bounds__(256) void k_refine(
    const float* __restrict__ knnt, const float4* __restrict__ xyzt,
    const unsigned short* __restrict__ cand, int* __restrict__ idxf) {
  int wid = blockIdx.x * 4 + (threadIdx.x >> 6);  // 0..32767
  int lane = threadIdx.x & 63;
  int phase = wid & 1;
  int qg = wid >> 1;           // (x*BB+b)*NN + q
  int q = qg & (NN - 1);
  int xb = qg >> 12;
  int b = xb & 1, x = xb >> 1;

  const unsigned short* cp = cand + (size_t)qg * 512 + phase * 256 + lane * 4;
  ushort4 c4 = *reinterpret_cast<const ushort4*>(cp);
  int i0 = c4.x, i1 = c4.y, i2 = c4.z, i3 = c4.w;
  float v0, v1, v2, v3;

  if (phase == 0) {
    // cosine: f32 dot of normalized rows (maximize)
    const float4* qr = reinterpret_cast<const float4*>(knnt + (size_t)qg * CH);
    const float* dbase = knnt + (size_t)((1 - x) * BB + b) * NN * CH;
    const float4* r0 = reinterpret_cast<const float4*>(dbase + (size_t)i0 * CH);
    const float4* r1 = reinterpret_cast<const float4*>(dbase + (size_t)i1 * CH);
    const float4* r2 = reinterpret_cast<const float4*>(dbase + (size_t)i2 * CH);
    const float4* r3 = reinterpret_cast<const float4*>(dbase + (size_t)i3 * CH);
    v0 = v1 = v2 = v3 = 0.f;
#pragma unroll 4
    for (int cb = 0; cb < 16; ++cb) {
      float4 qv = qr[cb];
      float4 p0 = r0[cb]; v0 += qv.x * p0.x + qv.y * p0.y + qv.z * p0.z + qv.w * p0.w;
      float4 p1 = r1[cb]; v1 += qv.x * p1.x + qv.y * p1.y + qv.z * p1.z + qv.w * p1.w;
      float4 p2 = r2[cb]; v2 += qv.x * p2.x + qv.y * p2.y + qv.z * p2.z + qv.w * p2.w;
      float4 p3 = r3[cb]; v3 += qv.x * p3.x + qv.y * p3.y + qv.z * p3.z + qv.w * p3.w;
    }
  } else {
    // euclid key = 2*q.p - |p|^2 (maximize), exact f32
    float4 q4 = xyzt[(size_t)(x * BB + b) * NN + q];
    const float4* dbx = xyzt + (size_t)((1 - x) * BB + b) * NN;
    float tx = 2.f * q4.x, ty = 2.f * q4.y, tz = 2.f * q4.z;
    float4 p;
    p = dbx[i0]; v0 = fmaf(tx, p.x, fmaf(ty, p.y, fmaf(tz, p.z, -p.w)));
    p = dbx[i1]; v1 = fmaf(tx, p.x, fmaf(ty, p.y, fmaf(tz, p.z, -p.w)));
    p = dbx[i2]; v2 = fmaf(tx, p.x, fmaf(ty, p.y, fmaf(tz, p.z, -p.w)));
    p = dbx[i3]; v3 = fmaf(tx, p.x, fmaf(ty, p.y, fmaf(tz, p.z, -p.w)));
  }

  // 8 rounds of wave-argmax extraction; lexicographic (v desc, idx asc) == top_k ties
  int win = 0;
#pragma unroll
  for (int k = 0; k < 8; ++k) {
    bool t01 = (v1 > v0) || (v1 == v0 && i1 < i0);
    float va = t01 ? v1 : v0; int ia = t01 ? i1 : i0;
    bool t23 = (v3 > v2) || (v3 == v2 && i3 < i2);
    float vb = t23 ? v3 : v2; int ib = t23 ? i3 : i2;
    bool tab = (vb > va) || (vb == va && ib < ia);
    float cv = tab ? vb : va; int ci = tab ? ib : ia;
#pragma unroll
    for (int s = 1; s < 64; s <<= 1) {
      float ov = __shfl_xor(cv, s, 64);
      int oi = __shfl_xor(ci, s, 64);
      bool bt = (ov > cv) || (ov == cv && oi < ci);
      cv = bt ? ov : cv; ci = bt ? oi : ci;
    }
    // remove winner (ids are unique across the candidate list)
    v0 = (i0 == ci) ? -1e38f : v0;
    v1 = (i1 == ci) ? -1e38f : v1;
    v2 = (i2 == ci) ? -1e38f : v2;
    v3 = (i3 == ci) ? -1e38f : v3;
    if (lane == k) win = ci;
  }
  if (lane < 8) idxf[(size_t)qg * 16 + phase * 8 + lane] = win;
}

// ---- fused gather + pos-conv + 2x MFMA MLP + neighbor max. One wave per query.
// M=16 neighbors, N=16-ch chunks (x4), K=32 (x2). A-frag: m=lane&15, k=(lane>>4)*8+j.
// B-frag: n=lane&15, k=(lane>>4)*8+j. D: col=lane&15, row=(lane>>4)*4+reg (m89/m120).
// Output: FLOAT32 (reference returns jnp.float32).
__global__ __launch_bounds__(256) void k_mlp(const float* __restrict__ fbuf,
                                             const float4* __restrict__ xyzt,
                                             const int* __restrict__ idxf,
                                             const float4* __restrict__ wp4,
                                             const __hip_bfloat16* __restrict__ wmb,
                                             const float* __restrict__ cn,
                                             float* __restrict__ out) {
  __shared__ __bf16 h1s[4 * 16 * 72];  // per-wave 16 rows x stride 72 (16B-aligned rows)
  const int t = threadIdx.x;
  const int wv = t >> 6, L = t & 63;
  const int lo = L & 15, g = L >> 4;
  int bid = blockIdx.x;  // 2*BB*(NN/4) = 4096
  const int qt = bid & (NN / 4 - 1);
  const int b = (bid >> 10) & 1;
  const int x = bid >> 11;
  const int q = qt * 4 + wv;

  // weight B-fragments resident in VGPRs: frag[tt][kc][j] = W[tt*16+lo][kc*32+g*8+j]
  bf16x8 w1f[4][2], w2f[4][2];
#pragma unroll
  for (int tt = 0; tt < 4; ++tt)
#pragma unroll
    for (int kc = 0; kc < 2; ++kc) {
      int e = tt * 16 + lo, c0 = kc * 32 + g * 8;
      w1f[tt][kc] = *reinterpret_cast<const bf16x8*>(wmb + e * 64 + c0);
      w2f[tt][kc] = *reinterpret_cast<const bf16x8*>(wmb + 4096 + e * 64 + c0);
    }

  const float* pq  = fbuf + ((size_t)((x ? 2 : 0) * BB + b)) * NN * CH;
  const float* pdb = fbuf + ((size_t)((x ? 3 : 1) * BB + b)) * NN * CH;
  const float4* qx  = xyzt + (size_t)(x * BB + b) * NN;
  const float4* dbx = xyzt + (size_t)((1 - x) * BB + b) * NN;

  const int m = lo;  // this lane's neighbor slot
  int jm = idxf[(((size_t)x * BB + b) * NN + q) * 16 + m];
  jm &= (NN - 1);  // defensive clamp: garbage idx -> finite-wrong, never OOB
  const float4 q4 = qx[q];
  const float4 p4 = dbx[jm];
  const float dx = p4.x - q4.x, dy = p4.y - q4.y, dz = p4.z - q4.z;
  const float* g2p = pdb + (size_t)jm * CH;
  const float* pqp = pq + (size_t)q * CH;

  // H0 built directly in A-fragment layout
  bf16x8 a0, a1;
#pragma unroll
  for (int kc = 0; kc < 2; ++kc) {
#pragma unroll
    for (int j = 0; j < 8; ++j) {
      int c = kc * 32 + g * 8 + j;
      float4 wp = wp4[c];
      float v = g2p[c] + pqp[c] + wp.x * dx + wp.y * dy + wp.z * dz + wp.w;
      v = lrelu(v);
      if (kc == 0) a0[j] = (__bf16)v; else a1[j] = (__bf16)v;
    }
  }

  // layer 1 -> LDS (D-layout write, A-layout read)
  __bf16* hrow = h1s + wv * 16 * 72;
#pragma unroll
  for (int tt = 0; tt < 4; ++tt) {
    float bv = cn[BM1_C + tt * 16 + lo];
    f32x4 acc = {bv, bv, bv, bv};
    acc = __builtin_amdgcn_mfma_f32_16x16x32_bf16(a0, w1f[tt][0], acc, 0, 0, 0);
    acc = __builtin_amdgcn_mfma_f32_16x16x32_bf16(a1, w1f[tt][1], acc, 0, 0, 0);
#pragma unroll
    for (int r = 0; r < 4; ++r) {
      float v = lrelu(acc[r]);
      hrow[(g * 4 + r) * 72 + tt * 16 + lo] = (__bf16)v;
    }
  }
  __syncthreads();
  bf16x8 h1a = *reinterpret_cast<const bf16x8*>(hrow + m * 72 + g * 8);
  bf16x8 h1b = *reinterpret_cast<const bf16x8*>(hrow + m * 72 + 32 + g * 8);

  // layer 2 + max over neighbors + store (f32)
  size_t obase = ((size_t)(x * BB + b) * CH) * NN;
#pragma unroll
  for (int tt = 0; tt < 4; ++tt) {
    float bv = cn[BM2_C + tt * 16 + lo];
    f32x4 acc = {bv, bv, bv, bv};
    acc = __builtin_amdgcn_mfma_f32_16x16x32_bf16(h1a, w2f[tt][0], acc, 0, 0, 0);
    acc = __builtin_amdgcn_mfma_f32_16x16x32_bf16(h1b, w2f[tt][1], acc, 0, 0, 0);
    float v = fmaxf(fmaxf(lrelu(acc[0]), lrelu(acc[1])), fmaxf(lrelu(acc[2]), lrelu(acc[3])));
    v = fmaxf(v, __shfl_xor(v, 16, 64));
    v = fmaxf(v, __shfl_xor(v, 32, 64));
    if (g == 0) out[obase + (size_t)(tt * 16 + lo) * NN + q] = v;
  }
}

// workspace layout (float units) — total ~11.94M floats = 47.7 MB
#define CN_OFF 0
#define FB_OFF ((size_t)CN_TOTAL)                      // 2,163,200
#define KT_OFF (FB_OFF + (size_t)4 * BB * NN * CH)     // +2,097,152
#define XZ_OFF (KT_OFF + (size_t)2 * BB * NN * CH)     // +1,048,576... (2*BB*NN*CH=2,097,152)
#define WP4_OFF (XZ_OFF + (size_t)2 * BB * NN * 4)     // +65,536
#define WMB_OFF (WP4_OFF + 256)                        // 8192 bf16 = 4096 floats
#define IDX_OFF (WMB_OFF + 4096)                       // 262,144 ints
#define FLAG_OFF (IDX_OFF + 262144)                    // 1 int (+pad)
#define KNB_OFF (FLAG_OFF + 4)                         // 2,097,152 bf16 = 1,048,576 floats
#define CAND_OFF (KNB_OFF + (size_t)BB * NN * CH)      // 8,388,608 u16 = 4,194,304 floats

extern "C" void kernel_launch(void* const* d_in, const int* in_sizes, int n_in,
                              void* d_out, int out_size, void* d_ws, size_t ws_size,
                              hipStream_t stream) {
  float* ws = (float*)d_ws;
  float* cn = ws + CN_OFF;
  int* flag = (int*)(ws + FLAG_OFF);

  k_detect<<<1, 64, 0, stream>>>((const unsigned short*)d_in[0], flag);
  k_ingest<<<(CN_TOTAL + 255) / 256, 256, 0, stream>>>(
      d_in[0], d_in[1], d_in[2], d_in[3], d_in[4], d_in[5], d_in[6], d_in[7],
      d_in[8], d_in[9], d_in[10], d_in[11], d_in[12], d_in[13], d_in[14], d_in[15],
      flag, cn);
  k_prep_wm<<<32, 256, 0, stream>>>(cn, (__hip_bfloat16*)(ws + WMB_OFF));
  k_prep_xyz<<<(2 * BB * NN) / 256, 256, 0, stream>>>(cn, (float4*)(ws + XZ_OFF));
  k_prep_wpos<<<1, 64, 0, stream>>>(cn, (float4*)(ws + WP4_OFF));
  k_prep_knn<<<(2 * BB * NN) / 256, 256, 0, stream>>>(cn, ws + KT_OFF);
  k_conv<<<4 * BB * (NN / 4), 256, 0, stream>>>(cn, ws + FB_OFF);
  k_prep_knnb<<<(2 * BB * NN * CH) / 4 / 256, 256, 0, stream>>>(
      ws + KT_OFF, (__hip_bfloat16*)(ws + KNB_OFF));
  k_knng<<<2 * BB * (NN / 16), 512, 0, stream>>>(
      (const __hip_bfloat16*)(ws + KNB_OFF), (const float4*)(ws + XZ_OFF),
      (unsigned short*)(ws + CAND_OFF));
  k_refine<<<(2 * 2 * BB * NN) / 4, 256, 0, stream>>>(
      ws + KT_OFF, (const float4*)(ws + XZ_OFF),
      (const unsigned short*)(ws + CAND_OFF), (int*)(ws + IDX_OFF));
  k_mlp<<<2 * BB * (NN / 4), 256, 0, stream>>>(ws + FB_OFF, (const float4*)(ws + XZ_OFF),
                                               (const int*)(ws + IDX_OFF), (const float4*)(ws + WP4_OFF),
                                               (const __hip_bfloat16*)(ws + WMB_OFF), cn,
                                               (float*)d_out);
}

// Round 2
// 314.431 us; speedup vs baseline: 2.6662x; 1.8345x over previous
//
#include <hip/hip_runtime.h>
#include <hip/hip_bf16.h>

#define BB 2
#define NN 4096
#define CH 64

typedef __bf16 bf16x8 __attribute__((ext_vector_type(8)));
typedef float f32x4 __attribute__((ext_vector_type(4)));

__device__ __forceinline__ float lrelu(float v) { return fmaxf(v, 0.1f * v); }
__device__ __forceinline__ float tobf(const __hip_bfloat16& h) { return __bfloat162float(h); }

// canonical f32 input region offsets (element offsets within cn)
#define PC1_C 0
#define PC2_C 24576
#define F1_C 49152
#define F2_C 573440
#define K1_C 1097728
#define K2_C 1622016
#define WT11_C 2146304
#define BT11_C 2150400
#define WT22_C 2150464
#define BT22_C 2154560
#define WPOS_C 2154624
#define BPOS_C 2154816
#define WM1_C 2154880
#define BM1_C 2158976
#define WM2_C 2159040
#define BM2_C 2163136
#define CN_TOTAL 2163200

// ---- packed selection key: (order-mapped bf16 score)<<12 | (4095-idx).
// Larger key = better (higher score, ties -> lower idx, matching top_k).
__device__ __forceinline__ unsigned pack_key(float s, int j) {
  __hip_bfloat16 hb = __float2bfloat16(s);
  unsigned h = *reinterpret_cast<unsigned short*>(&hb);
  unsigned m = h ^ (0x8000u | ((h >> 15) * 0x7FFFu));  // order-preserving map
  return (m << 12) | (unsigned)(4095 - j);
}

__device__ __forceinline__ unsigned umaxu(unsigned a, unsigned b) { return a > b ? a : b; }
__device__ __forceinline__ void casu(unsigned& a, unsigned& b) {
  unsigned mx = a > b ? a : b;
  unsigned mn = a > b ? b : a;
  a = mx; b = mn;
}

// merge 4 new keys into sorted-desc-8 bd[] (branch-free: sort4 + tail-max + bitonic8)
__device__ __forceinline__ void merge4(unsigned bd[8], unsigned k0, unsigned k1,
                                       unsigned k2, unsigned k3) {
  casu(k0, k1); casu(k2, k3); casu(k0, k2); casu(k1, k3); casu(k1, k2);
  bd[4] = umaxu(bd[4], k3); bd[5] = umaxu(bd[5], k2);
  bd[6] = umaxu(bd[6], k1); bd[7] = umaxu(bd[7], k0);
  casu(bd[0], bd[4]); casu(bd[1], bd[5]); casu(bd[2], bd[6]); casu(bd[3], bd[7]);
  casu(bd[0], bd[2]); casu(bd[1], bd[3]); casu(bd[4], bd[6]); casu(bd[5], bd[7]);
  casu(bd[0], bd[1]); casu(bd[2], bd[3]); casu(bd[4], bd[5]); casu(bd[6], bd[7]);
}

// ---- dtype detector: interpret pc1's first 4096 u16 words as bf16; f32 data's
// low mantissa halves produce ~45% exponents >= 140; true bf16 N(0,1) gives ~0.
__global__ void k_detect(const unsigned short* __restrict__ pc1raw, int* __restrict__ flag) {
  int lane = threadIdx.x;  // 64
  int bad = 0;
#pragma unroll
  for (int i = 0; i < 64; ++i) {
    unsigned short u = pc1raw[lane * 64 + i];
    int e = (u >> 7) & 0xFF;
    bad += (e >= 140) ? 1 : 0;  // |v| >= 2^13 or Inf/NaN
  }
#pragma unroll
  for (int s = 32; s; s >>= 1) bad += __shfl_xor(bad, s, 64);
  if (lane == 0) *flag = (bad > 16) ? 1 : 0;  // 1 = inputs are float32
}

// ---- ingest: convert all 16 inputs to canonical f32 (exact either way) + sanitize
__global__ __launch_bounds__(256) void k_ingest(
    const void* p0, const void* p1, const void* p2, const void* p3,
    const void* p4, const void* p5, const void* p6, const void* p7,
    const void* p8, const void* p9, const void* p10, const void* p11,
    const void* p12, const void* p13, const void* p14, const void* p15,
    const int* __restrict__ flag, float* __restrict__ dst) {
  const int cum[17] = {0, 24576, 49152, 573440, 1097728, 1622016, 2146304, 2150400,
                       2150464, 2154560, 2154624, 2154816, 2154880, 2158976, 2159040,
                       2163136, 2163200};
  size_t t = (size_t)blockIdx.x * 256 + threadIdx.x;
  if (t >= (size_t)CN_TOTAL) return;
  int seg = 0;
#pragma unroll
  for (int i = 1; i < 16; ++i) seg += (t >= (size_t)cum[i]) ? 1 : 0;
  size_t local = t - (size_t)cum[seg];
  const void* ptrs[16] = {p0, p1, p2, p3, p4, p5, p6, p7, p8, p9, p10, p11, p12, p13, p14, p15};
  const void* p = ptrs[seg];
  float v;
  if (*flag) v = ((const float*)p)[local];
  else       v = tobf(((const __hip_bfloat16*)p)[local]);
  if (!(v == v) || fabsf(v) > 1e30f) v = 0.f;  // sanitize (no-op on clean data)
  dst[t] = v;
}

// ---- Wm1/Wm2 -> bf16 canonical (row-major, Wm1 at [0,4096), Wm2 at [4096,8192))
__global__ void k_prep_wm(const float* __restrict__ cn, __hip_bfloat16* __restrict__ wmb) {
  int t = blockIdx.x * 256 + threadIdx.x;  // 8192
  float v = (t < 4096) ? cn[WM1_C + t] : cn[WM2_C + (t - 4096)];
  wmb[t] = __float2bfloat16(v);
}

// ---- prep: pc [B,3,N] f32 -> float4(x,y,z,|p|^2) [2][B][N]
__global__ __launch_bounds__(256) void k_prep_xyz(const float* __restrict__ cn,
                                                  float4* __restrict__ xyzt) {
  int t = blockIdx.x * 256 + threadIdx.x;  // 2*BB*NN threads
  int n = t & (NN - 1);
  int b = (t >> 12) & 1;
  int a = t >> 13;
  const float* p = cn + (a ? PC2_C : PC1_C) + (size_t)b * 3 * NN + n;
  float x = p[0], y = p[NN], z = p[2 * NN];
  xyzt[(size_t)(a * BB + b) * NN + n] = make_float4(x, y, z, x * x + y * y + z * z);
}

// ---- prep: W_pos [64,3] + b_pos [64] -> float4 per channel
__global__ void k_prep_wpos(const float* __restrict__ cn, float4* __restrict__ wp4) {
  int c = threadIdx.x;  // 64
  wp4[c] = make_float4(cn[WPOS_C + 3 * c], cn[WPOS_C + 3 * c + 1], cn[WPOS_C + 3 * c + 2],
                       cn[BPOS_C + c]);
}

// ---- prep: knn [B,64,N] f32 -> row-normalized f32 [2][B][N][64] + bf16 copy
__global__ __launch_bounds__(256) void k_prep_knn(const float* __restrict__ cn,
                                                  float* __restrict__ knnt,
                                                  __hip_bfloat16* __restrict__ knnb) {
  int t = blockIdx.x * 256 + threadIdx.x;  // 2*BB*NN
  int n = t & (NN - 1);
  int b = (t >> 12) & 1;
  int a = t >> 13;
  const float* col = cn + (a ? K2_C : K1_C) + (size_t)b * CH * NN + n;
  float s = 0.f;
#pragma unroll
  for (int c = 0; c < CH; ++c) { float v = col[(size_t)c * NN]; s += v * v; }
  float inv = 1.0f / sqrtf(s + 1e-8f);
  size_t row = (size_t)(a * BB + b) * NN + n;
  float* o = knnt + row * CH;
  __hip_bfloat16* ob = knnb + row * CH;
#pragma unroll
  for (int c = 0; c < CH; ++c) {
    float v = col[(size_t)c * NN] * inv;
    o[c] = v;
    ob[c] = __float2bfloat16(v);
  }
}

// ---- 1x1 convs: fbuf[sel][b][n][64], sel: 0=f1a(W11,f1) 1=f2a(W22,f2) 2=f2b(W11,f2) 3=f1b(W22,f1)
__global__ __launch_bounds__(256) void k_conv(const float* __restrict__ cn,
                                              float* __restrict__ fbuf) {
  __shared__ float wl[CH * CH];  // [c][d]
  int bid = blockIdx.x;          // 4*BB*(NN/4)
  int tile = bid & (NN / 4 - 1);
  int b = (bid >> 10) & 1;
  int sel = bid >> 11;
  const float* W = cn + ((sel == 0 || sel == 2) ? WT11_C : WT22_C);
  const float* bias = cn + ((sel == 0 || sel == 2) ? BT11_C : BT22_C);
  const float* feat = cn + ((sel == 0 || sel == 3) ? F1_C : F2_C);
  int t = threadIdx.x;
#pragma unroll
  for (int i = 0; i < 16; ++i) {
    int e = t * 16 + i;  // W[d][c] row-major -> wl[c][d]
    wl[(e & 63) * 64 + (e >> 6)] = W[e];
  }
  __syncthreads();
  int p = t >> 6, d = t & 63;
  int n = tile * 4 + p;
  const float* fc = feat + (size_t)b * CH * NN + n;
  float acc = bias[d];
#pragma unroll
  for (int c = 0; c < CH; ++c) acc += wl[c * 64 + d] * fc[(size_t)c * NN];
  fbuf[((size_t)(sel * BB + b) * NN + n) * CH + d] = acc;
}

// ======================================================================
// R7 fused KNN (replaces k_knng + k_refine + cand buffer):
//  - scan: bf16 MFMA (cos) / f32 fma (euclid), per-(lane,substream) top-8
//    kept as PACKED u32 keys via branch-free sort/merge networks
//    (38 umax/umin ops per 16-row tile -- no divergence, no insert8).
//  - in-block 5-step butterfly bitonic merge of 32 sorted-8 lists -> exact
//    bf16-key top-16 per query (margin: bf16 quant err ~2e-3 << rank gap
//    ~0.018; P[true top-8 not in bf16 top-16] ~ 1e-13/query).
//  - f32 rescore of only 16 candidates (2 lanes/cand + 1 shfl), exact
//    top-8 via 8-round butterfly argmax with idx tie-break.
// ======================================================================
__global__ __launch_bounds__(512, 4) void k_knn2(const __hip_bfloat16* __restrict__ knnb,
                                                 const float* __restrict__ knnt,
                                                 const float4* __restrict__ xyzt,
                                                 int* __restrict__ idxf) {
  __shared__ unsigned sk[16 * 8 * 33];  // [q][k][33 substream slots] 16.9 KB
  __shared__ int cidx[16 * 16];         // per-query top-16 candidate idx
  int bid = blockIdx.x;  // 2*BB*(NN/16) = 1024 : x(1) | b(1) | qt(8)
  int qt = bid & (NN / 16 - 1);
  int b = (bid >> 8) & 1;
  int x = bid >> 9;
  int w = threadIdx.x >> 6;
  int lane = threadIdx.x & 63;
  int lo = lane & 15, g = lane >> 4;
  int q0 = qt * 16;
  int j0 = w * (NN / 8);
  int ss = w * 4 + g;
  int hw = lane >> 5, sl = lane & 31;
  int qq = w * 2 + hw;  // extraction query (0..15)
  size_t qbase = (size_t)(x * BB + b) * NN;
  size_t dbase = (size_t)((1 - x) * BB + b) * NN;

  unsigned bd[8];

  // ======== phase 0: cosine scan (bf16 MFMA, packed-key top-8/substream) ========
  {
    const __hip_bfloat16* qb = knnb + (qbase + q0) * CH;
    bf16x8 qf0 = *reinterpret_cast<const bf16x8*>(qb + lo * CH + g * 8);
    bf16x8 qf1 = *reinterpret_cast<const bf16x8*>(qb + lo * CH + 32 + g * 8);
    const __hip_bfloat16* db = knnb + dbase * CH;
#pragma unroll
    for (int k = 0; k < 8; ++k) bd[k] = 0u;
#pragma unroll 2
    for (int t = 0; t < 32; ++t) {
      int jb = j0 + t * 16;
      const __hip_bfloat16* ar = db + (size_t)(jb + lo) * CH + g * 8;
      bf16x8 a0 = *reinterpret_cast<const bf16x8*>(ar);
      bf16x8 a1 = *reinterpret_cast<const bf16x8*>(ar + 32);
      f32x4 acc = {0.f, 0.f, 0.f, 0.f};
      acc = __builtin_amdgcn_mfma_f32_16x16x32_bf16(a0, qf0, acc, 0, 0, 0);
      acc = __builtin_amdgcn_mfma_f32_16x16x32_bf16(a1, qf1, acc, 0, 0, 0);
      int mb = jb + g * 4;  // D: col=lo (query), row=g*4+r (db row)
      merge4(bd, pack_key(acc[0], mb), pack_key(acc[1], mb + 1),
             pack_key(acc[2], mb + 2), pack_key(acc[3], mb + 3));
    }
  }
#pragma unroll
  for (int k = 0; k < 8; ++k) sk[(lo * 8 + k) * 33 + ss] = bd[k];
  __syncthreads();
  // ---- tree-merge to top-16 + f32 rescore + exact top-8 (cosine)
  {
    unsigned e[16];
#pragma unroll
    for (int k = 0; k < 8; ++k) e[k] = sk[(qq * 8 + k) * 33 + sl];
#pragma unroll
    for (int k = 8; k < 16; ++k) e[k] = 0u;
#pragma unroll
    for (int s = 1; s < 32; s <<= 1) {
      unsigned f[16];
#pragma unroll
      for (int k = 0; k < 16; ++k) f[k] = (unsigned)__shfl_xor((int)e[k], s, 64);
#pragma unroll
      for (int i = 0; i < 16; ++i) e[i] = umaxu(e[i], f[15 - i]);
      // bitonic-16 desc merge
      casu(e[0], e[8]); casu(e[1], e[9]); casu(e[2], e[10]); casu(e[3], e[11]);
      casu(e[4], e[12]); casu(e[5], e[13]); casu(e[6], e[14]); casu(e[7], e[15]);
      casu(e[0], e[4]); casu(e[1], e[5]); casu(e[2], e[6]); casu(e[3], e[7]);
      casu(e[8], e[12]); casu(e[9], e[13]); casu(e[10], e[14]); casu(e[11], e[15]);
      casu(e[0], e[2]); casu(e[1], e[3]); casu(e[4], e[6]); casu(e[5], e[7]);
      casu(e[8], e[10]); casu(e[9], e[11]); casu(e[12], e[14]); casu(e[13], e[15]);
      casu(e[0], e[1]); casu(e[2], e[3]); casu(e[4], e[5]); casu(e[6], e[7]);
      casu(e[8], e[9]); casu(e[10], e[11]); casu(e[12], e[13]); casu(e[14], e[15]);
    }
    if (sl == 0) {
#pragma unroll
      for (int k = 0; k < 16; ++k) cidx[qq * 16 + k] = 4095 - (int)(e[k] & 4095u);
    }
    int c = sl >> 1, hr = sl & 1;
    int idx = cidx[qq * 16 + c];  // same-wave LDS write->read (lockstep)
    const float4* qr = reinterpret_cast<const float4*>(knnt + (qbase + q0 + qq) * CH) + hr * 8;
    const float4* dr = reinterpret_cast<const float4*>(knnt + (dbase + idx) * CH) + hr * 8;
    float v = 0.f;
#pragma unroll
    for (int cb = 0; cb < 8; ++cb) {
      float4 qv = qr[cb], dv = dr[cb];
      v += qv.x * dv.x + qv.y * dv.y + qv.z * dv.z + qv.w * dv.w;
    }
    v += __shfl_xor(v, 1, 64);  // combine channel halves (commutative: bitwise same)
    // exact top-8 of 16 (2 copies each) with idx-asc tie-break
    float cv = v; int ci = idx; int wsel = 0;
#pragma unroll
    for (int k = 0; k < 8; ++k) {
      float av = cv; int ai = ci;
#pragma unroll
      for (int s = 1; s < 32; s <<= 1) {
        float ov = __shfl_xor(av, s, 64);
        int oi = __shfl_xor(ai, s, 64);
        bool bt = (ov > av) || (ov == av && oi < ai);
        av = bt ? ov : av; ai = bt ? oi : ai;
      }
      if (sl == k) wsel = ai;
      if (ci == ai) cv = -1e38f;
    }
    if (sl < 8) idxf[(qbase + q0 + qq) * 16 + sl] = wsel;
  }

  // ======== phase 1: euclid scan (exact f32 key = 2*q.p - |p|^2) ========
  __syncthreads();  // all phase-0 LDS reads done before reuse
  {
    const float4 q4 = xyzt[qbase + q0 + lo];
    const float4* dbx = xyzt + dbase;
    float tx = 2.f * q4.x, ty = 2.f * q4.y, tz = 2.f * q4.z;
#pragma unroll
    for (int k = 0; k < 8; ++k) bd[k] = 0u;
#pragma unroll 2
    for (int t = 0; t < 32; ++t) {
      int jb = j0 + t * 16 + g * 4;  // lane-group owns 4 rows per tile (disjoint)
      float4 p0 = dbx[jb], p1 = dbx[jb + 1], p2 = dbx[jb + 2], p3 = dbx[jb + 3];
      float v0 = fmaf(tx, p0.x, fmaf(ty, p0.y, fmaf(tz, p0.z, -p0.w)));
      float v1 = fmaf(tx, p1.x, fmaf(ty, p1.y, fmaf(tz, p1.z, -p1.w)));
      float v2 = fmaf(tx, p2.x, fmaf(ty, p2.y, fmaf(tz, p2.z, -p2.w)));
      float v3 = fmaf(tx, p3.x, fmaf(ty, p3.y, fmaf(tz, p3.z, -p3.w)));
      merge4(bd, pack_key(v0, jb), pack_key(v1, jb + 1),
             pack_key(v2, jb + 2), pack_key(v3, jb + 3));
    }
  }
#pragma unroll
  for (int k = 0; k < 8; ++k) sk[(lo * 8 + k) * 33 + ss] = bd[k];
  __syncthreads();
  // ---- tree-merge to top-16 + exact f32 rescore (4 fma) + top-8 (euclid)
  {
    unsigned e[16];
#pragma unroll
    for (int k = 0; k < 8; ++k) e[k] = sk[(qq * 8 + k) * 33 + sl];
#pragma unroll
    for (int k = 8; k < 16; ++k) e[k] = 0u;
#pragma unroll
    for (int s = 1; s < 32; s <<= 1) {
      unsigned f[16];
#pragma unroll
      for (int k = 0; k < 16; ++k) f[k] = (unsigned)__shfl_xor((int)e[k], s, 64);
#pragma unroll
      for (int i = 0; i < 16; ++i) e[i] = umaxu(e[i], f[15 - i]);
      casu(e[0], e[8]); casu(e[1], e[9]); casu(e[2], e[10]); casu(e[3], e[11]);
      casu(e[4], e[12]); casu(e[5], e[13]); casu(e[6], e[14]); casu(e[7], e[15]);
      casu(e[0], e[4]); casu(e[1], e[5]); casu(e[2], e[6]); casu(e[3], e[7]);
      casu(e[8], e[12]); casu(e[9], e[13]); casu(e[10], e[14]); casu(e[11], e[15]);
      casu(e[0], e[2]); casu(e[1], e[3]); casu(e[4], e[6]); casu(e[5], e[7]);
      casu(e[8], e[10]); casu(e[9], e[11]); casu(e[12], e[14]); casu(e[13], e[15]);
      casu(e[0], e[1]); casu(e[2], e[3]); casu(e[4], e[5]); casu(e[6], e[7]);
      casu(e[8], e[9]); casu(e[10], e[11]); casu(e[12], e[13]); casu(e[14], e[15]);
    }
    if (sl == 0) {
#pragma unroll
      for (int k = 0; k < 16; ++k) cidx[qq * 16 + k] = 4095 - (int)(e[k] & 4095u);
    }
    int c = sl >> 1;
    int idx = cidx[qq * 16 + c];
    const float4 q4 = xyzt[qbase + q0 + qq];
    float4 p = xyzt[dbase + idx];
    float v = fmaf(2.f * q4.x, p.x, fmaf(2.f * q4.y, p.y, fmaf(2.f * q4.z, p.z, -p.w)));
    float cv = v; int ci = idx; int wsel = 0;
#pragma unroll
    for (int k = 0; k < 8; ++k) {
      float av = cv; int ai = ci;
#pragma unroll
      for (int s = 1; s < 32; s <<= 1) {
        float ov = __shfl_xor(av, s, 64);
        int oi = __shfl_xor(ai, s, 64);
        bool bt = (ov > av) || (ov == av && oi < ai);
        av = bt ? ov : av; ai = bt ? oi : ai;
      }
      if (sl == k) wsel = ai;
      if (ci == ai) cv = -1e38f;
    }
    if (sl < 8) idxf[(qbase + q0 + qq) * 16 + 8 + sl] = wsel;
  }
}

// ---- fused gather + pos-conv + 2x MFMA MLP + neighbor max. One wave per query.
// M=16 neighbors, N=16-ch chunks (x4), K=32 (x2). A-frag: m=lane&15, k=(lane>>4)*8+j.
// B-frag: n=lane&15, k=(lane>>4)*8+j. D: col=lane&15, row=(lane>>4)*4+reg (m89/m120).
// Output: FLOAT32 (reference returns jnp.float32).
__global__ __launch_bounds__(256) void k_mlp(const float* __restrict__ fbuf,
                                             const float4* __restrict__ xyzt,
                                             const int* __restrict__ idxf,
                                             const float4* __restrict__ wp4,
                                             const __hip_bfloat16* __restrict__ wmb,
                                             const float* __restrict__ cn,
                                             float* __restrict__ out) {
  __shared__ __bf16 h1s[4 * 16 * 72];  // per-wave 16 rows x stride 72 (16B-aligned rows)
  const int t = threadIdx.x;
  const int wv = t >> 6, L = t & 63;
  const int lo = L & 15, g = L >> 4;
  int bid = blockIdx.x;  // 2*BB*(NN/4) = 4096
  const int qt = bid & (NN / 4 - 1);
  const int b = (bid >> 10) & 1;
  const int x = bid >> 11;
  const int q = qt * 4 + wv;

  // weight B-fragments resident in VGPRs: frag[tt][kc][j] = W[tt*16+lo][kc*32+g*8+j]
  bf16x8 w1f[4][2], w2f[4][2];
#pragma unroll
  for (int tt = 0; tt < 4; ++tt)
#pragma unroll
    for (int kc = 0; kc < 2; ++kc) {
      int e = tt * 16 + lo, c0 = kc * 32 + g * 8;
      w1f[tt][kc] = *reinterpret_cast<const bf16x8*>(wmb + e * 64 + c0);
      w2f[tt][kc] = *reinterpret_cast<const bf16x8*>(wmb + 4096 + e * 64 + c0);
    }

  const float* pq  = fbuf + ((size_t)((x ? 2 : 0) * BB + b)) * NN * CH;
  const float* pdb = fbuf + ((size_t)((x ? 3 : 1) * BB + b)) * NN * CH;
  const float4* qx  = xyzt + (size_t)(x * BB + b) * NN;
  const float4* dbx = xyzt + (size_t)((1 - x) * BB + b) * NN;

  const int m = lo;  // this lane's neighbor slot
  int jm = idxf[(((size_t)x * BB + b) * NN + q) * 16 + m];
  jm &= (NN - 1);  // defensive clamp: garbage idx -> finite-wrong, never OOB
  const float4 q4 = qx[q];
  const float4 p4 = dbx[jm];
  const float dx = p4.x - q4.x, dy = p4.y - q4.y, dz = p4.z - q4.z;
  const float* g2p = pdb + (size_t)jm * CH;
  const float* pqp = pq + (size_t)q * CH;

  // H0 built directly in A-fragment layout
  bf16x8 a0, a1;
#pragma unroll
  for (int kc = 0; kc < 2; ++kc) {
#pragma unroll
    for (int j = 0; j < 8; ++j) {
      int c = kc * 32 + g * 8 + j;
      float4 wp = wp4[c];
      float v = g2p[c] + pqp[c] + wp.x * dx + wp.y * dy + wp.z * dz + wp.w;
      v = lrelu(v);
      if (kc == 0) a0[j] = (__bf16)v; else a1[j] = (__bf16)v;
    }
  }

  // layer 1 -> LDS (D-layout write, A-layout read)
  __bf16* hrow = h1s + wv * 16 * 72;
#pragma unroll
  for (int tt = 0; tt < 4; ++tt) {
    float bv = cn[BM1_C + tt * 16 + lo];
    f32x4 acc = {bv, bv, bv, bv};
    acc = __builtin_amdgcn_mfma_f32_16x16x32_bf16(a0, w1f[tt][0], acc, 0, 0, 0);
    acc = __builtin_amdgcn_mfma_f32_16x16x32_bf16(a1, w1f[tt][1], acc, 0, 0, 0);
#pragma unroll
    for (int r = 0; r < 4; ++r) {
      float v = lrelu(acc[r]);
      hrow[(g * 4 + r) * 72 + tt * 16 + lo] = (__bf16)v;
    }
  }
  __syncthreads();
  bf16x8 h1a = *reinterpret_cast<const bf16x8*>(hrow + m * 72 + g * 8);
  bf16x8 h1b = *reinterpret_cast<const bf16x8*>(hrow + m * 72 + 32 + g * 8);

  // layer 2 + max over neighbors + store (f32)
  size_t obase = ((size_t)(x * BB + b) * CH) * NN;
#pragma unroll
  for (int tt = 0; tt < 4; ++tt) {
    float bv = cn[BM2_C + tt * 16 + lo];
    f32x4 acc = {bv, bv, bv, bv};
    acc = __builtin_amdgcn_mfma_f32_16x16x32_bf16(h1a, w2f[tt][0], acc, 0, 0, 0);
    acc = __builtin_amdgcn_mfma_f32_16x16x32_bf16(h1b, w2f[tt][1], acc, 0, 0, 0);
    float v = fmaxf(fmaxf(lrelu(acc[0]), lrelu(acc[1])), fmaxf(lrelu(acc[2]), lrelu(acc[3])));
    v = fmaxf(v, __shfl_xor(v, 16, 64));
    v = fmaxf(v, __shfl_xor(v, 32, 64));
    if (g == 0) out[obase + (size_t)(tt * 16 + lo) * NN + q] = v;
  }
}

// workspace layout (float units) — total ~7.74M floats = 31 MB
#define CN_OFF 0
#define FB_OFF ((size_t)CN_TOTAL)                      // 2,163,200
#define KT_OFF (FB_OFF + (size_t)4 * BB * NN * CH)     // fbuf 2,097,152
#define XZ_OFF (KT_OFF + (size_t)2 * BB * NN * CH)     // knnt 2,097,152
#define WP4_OFF (XZ_OFF + (size_t)2 * BB * NN * 4)     // xyzt 65,536
#define WMB_OFF (WP4_OFF + 256)                        // 8192 bf16 = 4096 floats
#define IDX_OFF (WMB_OFF + 4096)                       // 262,144 ints
#define FLAG_OFF (IDX_OFF + 262144)                    // 1 int (+pad)
#define KNB_OFF (FLAG_OFF + 4)                         // 2,097,152 bf16 = 1,048,576 floats

extern "C" void kernel_launch(void* const* d_in, const int* in_sizes, int n_in,
                              void* d_out, int out_size, void* d_ws, size_t ws_size,
                              hipStream_t stream) {
  float* ws = (float*)d_ws;
  float* cn = ws + CN_OFF;
  int* flag = (int*)(ws + FLAG_OFF);

  k_detect<<<1, 64, 0, stream>>>((const unsigned short*)d_in[0], flag);
  k_ingest<<<(CN_TOTAL + 255) / 256, 256, 0, stream>>>(
      d_in[0], d_in[1], d_in[2], d_in[3], d_in[4], d_in[5], d_in[6], d_in[7],
      d_in[8], d_in[9], d_in[10], d_in[11], d_in[12], d_in[13], d_in[14], d_in[15],
      flag, cn);
  k_prep_wm<<<32, 256, 0, stream>>>(cn, (__hip_bfloat16*)(ws + WMB_OFF));
  k_prep_xyz<<<(2 * BB * NN) / 256, 256, 0, stream>>>(cn, (float4*)(ws + XZ_OFF));
  k_prep_wpos<<<1, 64, 0, stream>>>(cn, (float4*)(ws + WP4_OFF));
  k_prep_knn<<<(2 * BB * NN) / 256, 256, 0, stream>>>(cn, ws + KT_OFF,
                                                     (__hip_bfloat16*)(ws + KNB_OFF));
  k_conv<<<4 * BB * (NN / 4), 256, 0, stream>>>(cn, ws + FB_OFF);
  k_knn2<<<2 * BB * (NN / 16), 512, 0, stream>>>(
      (const __hip_bfloat16*)(ws + KNB_OFF), ws + KT_OFF,
      (const float4*)(ws + XZ_OFF), (int*)(ws + IDX_OFF));
  k_mlp<<<2 * BB * (NN / 4), 256, 0, stream>>>(ws + FB_OFF, (const float4*)(ws + XZ_OFF),
                                               (const int*)(ws + IDX_OFF), (const float4*)(ws + WP4_OFF),
                                               (const __hip_bfloat16*)(ws + WMB_OFF), cn,
                                               (float*)d_out);
}

// Round 3
// 311.724 us; speedup vs baseline: 2.6894x; 1.0087x over previous
//
#include <hip/hip_runtime.h>
#include <hip/hip_bf16.h>

#define BB 2
#define NN 4096
#define CH 64

typedef __bf16 bf16x8 __attribute__((ext_vector_type(8)));
typedef float f32x4 __attribute__((ext_vector_type(4)));

__device__ __forceinline__ float lrelu(float v) { return fmaxf(v, 0.1f * v); }
__device__ __forceinline__ float tobf(const __hip_bfloat16& h) { return __bfloat162float(h); }

// canonical f32 input region offsets (element offsets within cn)
#define PC1_C 0
#define PC2_C 24576
#define F1_C 49152
#define F2_C 573440
#define K1_C 1097728
#define K2_C 1622016
#define WT11_C 2146304
#define BT11_C 2150400
#define WT22_C 2150464
#define BT22_C 2154560
#define WPOS_C 2154624
#define BPOS_C 2154816
#define WM1_C 2154880
#define BM1_C 2158976
#define WM2_C 2159040
#define BM2_C 2163136
#define CN_TOTAL 2163200

// ---- packed selection keys: (order-mapped f32 score truncated to 20 bits)<<12 | (4095-idx)
// Larger key = better (higher score, ties -> lower idx, matching top_k tie rule).
// Cosine scores are MFMA dots of unit vectors: acc in [-1.1,1.1]; +4.0 makes the
// f32 bit pattern directly monotone (granularity ~2e-3 << rank-8/9 gap ~0.018).
// Euclid scores (2q.p-|p|^2) are signed: full sign-fold map (3 ops), granularity
// ~2^-12 relative -- 10x finer than the old bf16 key there.
__device__ __forceinline__ unsigned fmap(float s) {
  unsigned u = __float_as_uint(s);
  return u ^ ((unsigned)((int)u >> 31) | 0x80000000u);
}

__device__ __forceinline__ unsigned umaxu(unsigned a, unsigned b) { return a > b ? a : b; }
__device__ __forceinline__ void casu(unsigned& a, unsigned& b) {
  unsigned mx = a > b ? a : b;
  unsigned mn = a > b ? b : a;
  a = mx; b = mn;
}

// bitonic-8 desc merge (input bitonic -> sorted desc)
__device__ __forceinline__ void bitonic8(unsigned bd[8]) {
  casu(bd[0], bd[4]); casu(bd[1], bd[5]); casu(bd[2], bd[6]); casu(bd[3], bd[7]);
  casu(bd[0], bd[2]); casu(bd[1], bd[3]); casu(bd[4], bd[6]); casu(bd[5], bd[7]);
  casu(bd[0], bd[1]); casu(bd[2], bd[3]); casu(bd[4], bd[5]); casu(bd[6], bd[7]);
}

// merge 4 new keys into sorted-desc-8 bd[] (branch-free: sort4 + tail-max + bitonic8)
__device__ __forceinline__ void merge4(unsigned bd[8], unsigned k0, unsigned k1,
                                       unsigned k2, unsigned k3) {
  casu(k0, k1); casu(k2, k3); casu(k0, k2); casu(k1, k3); casu(k1, k2);
  bd[4] = umaxu(bd[4], k3); bd[5] = umaxu(bd[5], k2);
  bd[6] = umaxu(bd[6], k1); bd[7] = umaxu(bd[7], k0);
  bitonic8(bd);
}

// top-8 of union of two sorted-desc-8 lists -> a[]
__device__ __forceinline__ void merge88(unsigned a[8], const unsigned b[8]) {
  a[0] = umaxu(a[0], b[7]); a[1] = umaxu(a[1], b[6]);
  a[2] = umaxu(a[2], b[5]); a[3] = umaxu(a[3], b[4]);
  a[4] = umaxu(a[4], b[3]); a[5] = umaxu(a[5], b[2]);
  a[6] = umaxu(a[6], b[1]); a[7] = umaxu(a[7], b[0]);
  bitonic8(a);
}

// ---- dtype detector: interpret pc1's first 4096 u16 words as bf16; f32 data's
// low mantissa halves produce ~45% exponents >= 140; true bf16 N(0,1) gives ~0.
__global__ void k_detect(const unsigned short* __restrict__ pc1raw, int* __restrict__ flag) {
  int lane = threadIdx.x;  // 64
  int bad = 0;
#pragma unroll
  for (int i = 0; i < 64; ++i) {
    unsigned short u = pc1raw[lane * 64 + i];
    int e = (u >> 7) & 0xFF;
    bad += (e >= 140) ? 1 : 0;  // |v| >= 2^13 or Inf/NaN
  }
#pragma unroll
  for (int s = 32; s; s >>= 1) bad += __shfl_xor(bad, s, 64);
  if (lane == 0) *flag = (bad > 16) ? 1 : 0;  // 1 = inputs are float32
}

// ---- ingest: convert all 16 inputs to canonical f32 (exact either way) + sanitize
__global__ __launch_bounds__(256) void k_ingest(
    const void* p0, const void* p1, const void* p2, const void* p3,
    const void* p4, const void* p5, const void* p6, const void* p7,
    const void* p8, const void* p9, const void* p10, const void* p11,
    const void* p12, const void* p13, const void* p14, const void* p15,
    const int* __restrict__ flag, float* __restrict__ dst) {
  const int cum[17] = {0, 24576, 49152, 573440, 1097728, 1622016, 2146304, 2150400,
                       2150464, 2154560, 2154624, 2154816, 2154880, 2158976, 2159040,
                       2163136, 2163200};
  size_t t = (size_t)blockIdx.x * 256 + threadIdx.x;
  if (t >= (size_t)CN_TOTAL) return;
  int seg = 0;
#pragma unroll
  for (int i = 1; i < 16; ++i) seg += (t >= (size_t)cum[i]) ? 1 : 0;
  size_t local = t - (size_t)cum[seg];
  const void* ptrs[16] = {p0, p1, p2, p3, p4, p5, p6, p7, p8, p9, p10, p11, p12, p13, p14, p15};
  const void* p = ptrs[seg];
  float v;
  if (*flag) v = ((const float*)p)[local];
  else       v = tobf(((const __hip_bfloat16*)p)[local]);
  if (!(v == v) || fabsf(v) > 1e30f) v = 0.f;  // sanitize (no-op on clean data)
  dst[t] = v;
}

// ---- fused misc prep: blocks 0..31 Wm->bf16, 32..95 xyz float4, 96 wpos
__global__ __launch_bounds__(256) void k_prep_misc(const float* __restrict__ cn,
                                                   __hip_bfloat16* __restrict__ wmb,
                                                   float4* __restrict__ xyzt,
                                                   float4* __restrict__ wp4) {
  int bid = blockIdx.x;
  if (bid < 32) {
    int t = bid * 256 + threadIdx.x;  // 8192
    float v = (t < 4096) ? cn[WM1_C + t] : cn[WM2_C + (t - 4096)];
    wmb[t] = __float2bfloat16(v);
  } else if (bid < 96) {
    int t = (bid - 32) * 256 + threadIdx.x;  // 2*BB*NN = 16384
    int n = t & (NN - 1);
    int b = (t >> 12) & 1;
    int a = t >> 13;
    const float* p = cn + (a ? PC2_C : PC1_C) + (size_t)b * 3 * NN + n;
    float x = p[0], y = p[NN], z = p[2 * NN];
    xyzt[(size_t)(a * BB + b) * NN + n] = make_float4(x, y, z, x * x + y * y + z * z);
  } else {
    int c = threadIdx.x;
    if (c < 64)
      wp4[c] = make_float4(cn[WPOS_C + 3 * c], cn[WPOS_C + 3 * c + 1],
                           cn[WPOS_C + 3 * c + 2], cn[BPOS_C + c]);
  }
}

// ---- prep: knn [B,64,N] f32 -> row-normalized f32 [2][B][N][64] + bf16 copy
__global__ __launch_bounds__(256) void k_prep_knn(const float* __restrict__ cn,
                                                  float* __restrict__ knnt,
                                                  __hip_bfloat16* __restrict__ knnb) {
  int t = blockIdx.x * 256 + threadIdx.x;  // 2*BB*NN
  int n = t & (NN - 1);
  int b = (t >> 12) & 1;
  int a = t >> 13;
  const float* col = cn + (a ? K2_C : K1_C) + (size_t)b * CH * NN + n;
  float s = 0.f;
#pragma unroll
  for (int c = 0; c < CH; ++c) { float v = col[(size_t)c * NN]; s += v * v; }
  float inv = 1.0f / sqrtf(s + 1e-8f);
  size_t row = (size_t)(a * BB + b) * NN + n;
  float* o = knnt + row * CH;
  __hip_bfloat16* ob = knnb + row * CH;
#pragma unroll
  for (int c = 0; c < CH; ++c) {
    float v = col[(size_t)c * NN] * inv;
    o[c] = v;
    ob[c] = __float2bfloat16(v);
  }
}

// ---- 1x1 convs: fbuf[sel][b][n][64], sel: 0=f1a(W11,f1) 1=f2a(W22,f2) 2=f2b(W11,f2) 3=f1b(W22,f1)
__global__ __launch_bounds__(256) void k_conv(const float* __restrict__ cn,
                                              float* __restrict__ fbuf) {
  __shared__ float wl[CH * CH];  // [c][d]
  int bid = blockIdx.x;          // 4*BB*(NN/4)
  int tile = bid & (NN / 4 - 1);
  int b = (bid >> 10) & 1;
  int sel = bid >> 11;
  const float* W = cn + ((sel == 0 || sel == 2) ? WT11_C : WT22_C);
  const float* bias = cn + ((sel == 0 || sel == 2) ? BT11_C : BT22_C);
  const float* feat = cn + ((sel == 0 || sel == 3) ? F1_C : F2_C);
  int t = threadIdx.x;
#pragma unroll
  for (int i = 0; i < 16; ++i) {
    int e = t * 16 + i;  // W[d][c] row-major -> wl[c][d]
    wl[(e & 63) * 64 + (e >> 6)] = W[e];
  }
  __syncthreads();
  int p = t >> 6, d = t & 63;
  int n = tile * 4 + p;
  const float* fc = feat + (size_t)b * CH * NN + n;
  float acc = bias[d];
#pragma unroll
  for (int c = 0; c < CH; ++c) acc += wl[c * 64 + d] * fc[(size_t)c * NN];
  fbuf[((size_t)(sel * BB + b) * NN + n) * CH + d] = acc;
}

// ======================================================================
// R8 k_knn3: fused cos+euclid scan, 4 independent merge chains (even/odd
// tiles x 2 phases -> dep-chains broken, ILP up), cheap f32-direct packed
// keys, single barrier. Tree-merge to bf-key top-16 per query + exact f32
// rescore of 16 + exact top-8 (idx tie-break) -- same proven extraction.
// ======================================================================
__global__ __launch_bounds__(512, 4) void k_knn3(const __hip_bfloat16* __restrict__ knnb,
                                                 const float* __restrict__ knnt,
                                                 const float4* __restrict__ xyzt,
                                                 int* __restrict__ idxf) {
  __shared__ unsigned skc[16 * 8 * 33];  // cosine dumps, 16.5 KB
  __shared__ unsigned ske[16 * 8 * 33];  // euclid dumps, 16.5 KB
  __shared__ int cidx[16 * 16];
  int bid = blockIdx.x;  // 2*BB*(NN/16) = 1024 : x(1) | b(1) | qt(8)
  int qt = bid & (NN / 16 - 1);
  int b = (bid >> 8) & 1;
  int x = bid >> 9;
  int w = threadIdx.x >> 6;
  int lane = threadIdx.x & 63;
  int lo = lane & 15, g = lane >> 4;
  int q0 = qt * 16;
  int j0 = w * (NN / 8);
  int ss = w * 4 + g;
  int hw = lane >> 5, sl = lane & 31;
  int qq = w * 2 + hw;  // extraction query (0..15)
  size_t qbase = (size_t)(x * BB + b) * NN;
  size_t dbase = (size_t)((1 - x) * BB + b) * NN;

  // resident query data
  const __hip_bfloat16* qb = knnb + (qbase + q0) * CH;
  bf16x8 qf0 = *reinterpret_cast<const bf16x8*>(qb + lo * CH + g * 8);
  bf16x8 qf1 = *reinterpret_cast<const bf16x8*>(qb + lo * CH + 32 + g * 8);
  const __hip_bfloat16* db = knnb + dbase * CH;
  const float4 q4 = xyzt[qbase + q0 + lo];
  const float4* dbx = xyzt + dbase;
  float tx = 2.f * q4.x, ty = 2.f * q4.y, tz = 2.f * q4.z;

  unsigned bc0[8], bc1[8], be0[8], be1[8];
#pragma unroll
  for (int k = 0; k < 8; ++k) { bc0[k] = 0u; bc1[k] = 0u; be0[k] = 0u; be1[k] = 0u; }

  auto TILE = [&](unsigned (&bc)[8], unsigned (&be)[8], int jb) {
    unsigned rc = (unsigned)(4095 - jb - g * 4);  // rev-idx base (rows jb+g*4..+3)
    // cosine: 16 db rows x 16 queries via 2 MFMA
    const __hip_bfloat16* ar = db + (size_t)(jb + lo) * CH + g * 8;
    bf16x8 a0 = *reinterpret_cast<const bf16x8*>(ar);
    bf16x8 a1 = *reinterpret_cast<const bf16x8*>(ar + 32);
    f32x4 acc = {0.f, 0.f, 0.f, 0.f};
    acc = __builtin_amdgcn_mfma_f32_16x16x32_bf16(a0, qf0, acc, 0, 0, 0);
    acc = __builtin_amdgcn_mfma_f32_16x16x32_bf16(a1, qf1, acc, 0, 0, 0);
    // euclid: same 4 rows (jb+g*4+r), exact f32 key = 2q.p - |p|^2
    int je = jb + g * 4;
    float4 p0 = dbx[je], p1 = dbx[je + 1], p2 = dbx[je + 2], p3 = dbx[je + 3];
    float v0 = fmaf(tx, p0.x, fmaf(ty, p0.y, fmaf(tz, p0.z, -p0.w)));
    float v1 = fmaf(tx, p1.x, fmaf(ty, p1.y, fmaf(tz, p1.z, -p1.w)));
    float v2 = fmaf(tx, p2.x, fmaf(ty, p2.y, fmaf(tz, p2.z, -p2.w)));
    float v3 = fmaf(tx, p3.x, fmaf(ty, p3.y, fmaf(tz, p3.z, -p3.w)));
    merge4(bc, (__float_as_uint(acc[0] + 4.0f) & 0xFFFFF000u) | rc,
               (__float_as_uint(acc[1] + 4.0f) & 0xFFFFF000u) | (rc - 1),
               (__float_as_uint(acc[2] + 4.0f) & 0xFFFFF000u) | (rc - 2),
               (__float_as_uint(acc[3] + 4.0f) & 0xFFFFF000u) | (rc - 3));
    merge4(be, (fmap(v0) & 0xFFFFF000u) | rc,
               (fmap(v1) & 0xFFFFF000u) | (rc - 1),
               (fmap(v2) & 0xFFFFF000u) | (rc - 2),
               (fmap(v3) & 0xFFFFF000u) | (rc - 3));
  };

  for (int t = 0; t < 16; ++t) {
    TILE(bc0, be0, j0 + (2 * t) * 16);
    TILE(bc1, be1, j0 + (2 * t + 1) * 16);
  }
  merge88(bc0, bc1);
  merge88(be0, be1);
#pragma unroll
  for (int k = 0; k < 8; ++k) {
    skc[(lo * 8 + k) * 33 + ss] = bc0[k];
    ske[(lo * 8 + k) * 33 + ss] = be0[k];
  }
  __syncthreads();

  // ---- cosine extraction: tree-merge top-16 + f32 rescore + exact top-8
  {
    unsigned e[16];
#pragma unroll
    for (int k = 0; k < 8; ++k) e[k] = skc[(qq * 8 + k) * 33 + sl];
#pragma unroll
    for (int k = 8; k < 16; ++k) e[k] = 0u;
#pragma unroll
    for (int s = 1; s < 32; s <<= 1) {
      unsigned f[16];
#pragma unroll
      for (int k = 0; k < 16; ++k) f[k] = (unsigned)__shfl_xor((int)e[k], s, 64);
#pragma unroll
      for (int i = 0; i < 16; ++i) e[i] = umaxu(e[i], f[15 - i]);
      // bitonic-16 desc merge
      casu(e[0], e[8]); casu(e[1], e[9]); casu(e[2], e[10]); casu(e[3], e[11]);
      casu(e[4], e[12]); casu(e[5], e[13]); casu(e[6], e[14]); casu(e[7], e[15]);
      casu(e[0], e[4]); casu(e[1], e[5]); casu(e[2], e[6]); casu(e[3], e[7]);
      casu(e[8], e[12]); casu(e[9], e[13]); casu(e[10], e[14]); casu(e[11], e[15]);
      casu(e[0], e[2]); casu(e[1], e[3]); casu(e[4], e[6]); casu(e[5], e[7]);
      casu(e[8], e[10]); casu(e[9], e[11]); casu(e[12], e[14]); casu(e[13], e[15]);
      casu(e[0], e[1]); casu(e[2], e[3]); casu(e[4], e[5]); casu(e[6], e[7]);
      casu(e[8], e[9]); casu(e[10], e[11]); casu(e[12], e[13]); casu(e[14], e[15]);
    }
    if (sl == 0) {
#pragma unroll
      for (int k = 0; k < 16; ++k) cidx[qq * 16 + k] = 4095 - (int)(e[k] & 4095u);
    }
    int c = sl >> 1, hr = sl & 1;
    int idx = cidx[qq * 16 + c];  // same-wave LDS write->read (lockstep)
    const float4* qr = reinterpret_cast<const float4*>(knnt + (qbase + q0 + qq) * CH) + hr * 8;
    const float4* dr = reinterpret_cast<const float4*>(knnt + (dbase + idx) * CH) + hr * 8;
    float v = 0.f;
#pragma unroll 4
    for (int cb = 0; cb < 8; ++cb) {
      float4 qv = qr[cb], dv = dr[cb];
      v += qv.x * dv.x + qv.y * dv.y + qv.z * dv.z + qv.w * dv.w;
    }
    v += __shfl_xor(v, 1, 64);  // combine channel halves (commutative: bitwise same)
    float cv = v; int ci = idx; int wsel = 0;
#pragma unroll
    for (int k = 0; k < 8; ++k) {
      float av = cv; int ai = ci;
#pragma unroll
      for (int s = 1; s < 32; s <<= 1) {
        float ov = __shfl_xor(av, s, 64);
        int oi = __shfl_xor(ai, s, 64);
        bool bt = (ov > av) || (ov == av && oi < ai);
        av = bt ? ov : av; ai = bt ? oi : ai;
      }
      if (sl == k) wsel = ai;
      if (ci == ai) cv = -1e38f;
    }
    if (sl < 8) idxf[(qbase + q0 + qq) * 16 + sl] = wsel;
  }

  // ---- euclid extraction: tree-merge top-16 + exact f32 rescore (4 fma) + top-8
  {
    unsigned e[16];
#pragma unroll
    for (int k = 0; k < 8; ++k) e[k] = ske[(qq * 8 + k) * 33 + sl];
#pragma unroll
    for (int k = 8; k < 16; ++k) e[k] = 0u;
#pragma unroll
    for (int s = 1; s < 32; s <<= 1) {
      unsigned f[16];
#pragma unroll
      for (int k = 0; k < 16; ++k) f[k] = (unsigned)__shfl_xor((int)e[k], s, 64);
#pragma unroll
      for (int i = 0; i < 16; ++i) e[i] = umaxu(e[i], f[15 - i]);
      casu(e[0], e[8]); casu(e[1], e[9]); casu(e[2], e[10]); casu(e[3], e[11]);
      casu(e[4], e[12]); casu(e[5], e[13]); casu(e[6], e[14]); casu(e[7], e[15]);
      casu(e[0], e[4]); casu(e[1], e[5]); casu(e[2], e[6]); casu(e[3], e[7]);
      casu(e[8], e[12]); casu(e[9], e[13]); casu(e[10], e[14]); casu(e[11], e[15]);
      casu(e[0], e[2]); casu(e[1], e[3]); casu(e[4], e[6]); casu(e[5], e[7]);
      casu(e[8], e[10]); casu(e[9], e[11]); casu(e[12], e[14]); casu(e[13], e[15]);
      casu(e[0], e[1]); casu(e[2], e[3]); casu(e[4], e[5]); casu(e[6], e[7]);
      casu(e[8], e[9]); casu(e[10], e[11]); casu(e[12], e[13]); casu(e[14], e[15]);
    }
    if (sl == 0) {
#pragma unroll
      for (int k = 0; k < 16; ++k) cidx[qq * 16 + k] = 4095 - (int)(e[k] & 4095u);
    }
    int c = sl >> 1;
    int idx = cidx[qq * 16 + c];
    const float4 qx4 = xyzt[qbase + q0 + qq];
    float4 p = xyzt[dbase + idx];
    float v = fmaf(2.f * qx4.x, p.x, fmaf(2.f * qx4.y, p.y, fmaf(2.f * qx4.z, p.z, -p.w)));
    float cv = v; int ci = idx; int wsel = 0;
#pragma unroll
    for (int k = 0; k < 8; ++k) {
      float av = cv; int ai = ci;
#pragma unroll
      for (int s = 1; s < 32; s <<= 1) {
        float ov = __shfl_xor(av, s, 64);
        int oi = __shfl_xor(ai, s, 64);
        bool bt = (ov > av) || (ov == av && oi < ai);
        av = bt ? ov : av; ai = bt ? oi : ai;
      }
      if (sl == k) wsel = ai;
      if (ci == ai) cv = -1e38f;
    }
    if (sl < 8) idxf[(qbase + q0 + qq) * 16 + 8 + sl] = wsel;
  }
}

// ---- fused gather + pos-conv + 2x MFMA MLP + neighbor max. One wave per query.
// M=16 neighbors, N=16-ch chunks (x4), K=32 (x2). A-frag: m=lane&15, k=(lane>>4)*8+j.
// B-frag: n=lane&15, k=(lane>>4)*8+j. D: col=lane&15, row=(lane>>4)*4+reg (m89/m120).
// Output: FLOAT32 (reference returns jnp.float32).
__global__ __launch_bounds__(256) void k_mlp(const float* __restrict__ fbuf,
                                             const float4* __restrict__ xyzt,
                                             const int* __restrict__ idxf,
                                             const float4* __restrict__ wp4,
                                             const __hip_bfloat16* __restrict__ wmb,
                                             const float* __restrict__ cn,
                                             float* __restrict__ out) {
  __shared__ __bf16 h1s[4 * 16 * 72];  // per-wave 16 rows x stride 72 (16B-aligned rows)
  const int t = threadIdx.x;
  const int wv = t >> 6, L = t & 63;
  const int lo = L & 15, g = L >> 4;
  int bid = blockIdx.x;  // 2*BB*(NN/4) = 4096
  const int qt = bid & (NN / 4 - 1);
  const int b = (bid >> 10) & 1;
  const int x = bid >> 11;
  const int q = qt * 4 + wv;

  // weight B-fragments resident in VGPRs: frag[tt][kc][j] = W[tt*16+lo][kc*32+g*8+j]
  bf16x8 w1f[4][2], w2f[4][2];
#pragma unroll
  for (int tt = 0; tt < 4; ++tt)
#pragma unroll
    for (int kc = 0; kc < 2; ++kc) {
      int e = tt * 16 + lo, c0 = kc * 32 + g * 8;
      w1f[tt][kc] = *reinterpret_cast<const bf16x8*>(wmb + e * 64 + c0);
      w2f[tt][kc] = *reinterpret_cast<const bf16x8*>(wmb + 4096 + e * 64 + c0);
    }

  const float* pq  = fbuf + ((size_t)((x ? 2 : 0) * BB + b)) * NN * CH;
  const float* pdb = fbuf + ((size_t)((x ? 3 : 1) * BB + b)) * NN * CH;
  const float4* qx  = xyzt + (size_t)(x * BB + b) * NN;
  const float4* dbx = xyzt + (size_t)((1 - x) * BB + b) * NN;

  const int m = lo;  // this lane's neighbor slot
  int jm = idxf[(((size_t)x * BB + b) * NN + q) * 16 + m];
  jm &= (NN - 1);  // defensive clamp: garbage idx -> finite-wrong, never OOB
  const float4 q4 = qx[q];
  const float4 p4 = dbx[jm];
  const float dx = p4.x - q4.x, dy = p4.y - q4.y, dz = p4.z - q4.z;

  // vectorized gathers: this lane's 16 channels = [g*8, g*8+8) and [32+g*8, +8)
  const float4* g2v = reinterpret_cast<const float4*>(pdb + (size_t)jm * CH);
  const float4* pqv = reinterpret_cast<const float4*>(pq + (size_t)q * CH);
  float hv[16];
  {
    float4 t0 = g2v[g * 2], t1 = g2v[g * 2 + 1], t2 = g2v[g * 2 + 8], t3 = g2v[g * 2 + 9];
    float4 u0 = pqv[g * 2], u1 = pqv[g * 2 + 1], u2 = pqv[g * 2 + 8], u3 = pqv[g * 2 + 9];
    hv[0] = t0.x + u0.x; hv[1] = t0.y + u0.y; hv[2] = t0.z + u0.z; hv[3] = t0.w + u0.w;
    hv[4] = t1.x + u1.x; hv[5] = t1.y + u1.y; hv[6] = t1.z + u1.z; hv[7] = t1.w + u1.w;
    hv[8] = t2.x + u2.x; hv[9] = t2.y + u2.y; hv[10] = t2.z + u2.z; hv[11] = t2.w + u2.w;
    hv[12] = t3.x + u3.x; hv[13] = t3.y + u3.y; hv[14] = t3.z + u3.z; hv[15] = t3.w + u3.w;
  }

  // H0 built directly in A-fragment layout
  bf16x8 a0, a1;
#pragma unroll
  for (int kc = 0; kc < 2; ++kc) {
#pragma unroll
    for (int j = 0; j < 8; ++j) {
      int c = kc * 32 + g * 8 + j;
      float4 wp = wp4[c];
      float v = hv[kc * 8 + j] + wp.x * dx + wp.y * dy + wp.z * dz + wp.w;
      v = lrelu(v);
      if (kc == 0) a0[j] = (__bf16)v; else a1[j] = (__bf16)v;
    }
  }

  // layer 1 -> LDS (D-layout write, A-layout read)
  __bf16* hrow = h1s + wv * 16 * 72;
#pragma unroll
  for (int tt = 0; tt < 4; ++tt) {
    float bv = cn[BM1_C + tt * 16 + lo];
    f32x4 acc = {bv, bv, bv, bv};
    acc = __builtin_amdgcn_mfma_f32_16x16x32_bf16(a0, w1f[tt][0], acc, 0, 0, 0);
    acc = __builtin_amdgcn_mfma_f32_16x16x32_bf16(a1, w1f[tt][1], acc, 0, 0, 0);
#pragma unroll
    for (int r = 0; r < 4; ++r) {
      float v = lrelu(acc[r]);
      hrow[(g * 4 + r) * 72 + tt * 16 + lo] = (__bf16)v;
    }
  }
  __syncthreads();
  bf16x8 h1a = *reinterpret_cast<const bf16x8*>(hrow + m * 72 + g * 8);
  bf16x8 h1b = *reinterpret_cast<const bf16x8*>(hrow + m * 72 + 32 + g * 8);

  // layer 2 + max over neighbors + store (f32)
  size_t obase = ((size_t)(x * BB + b) * CH) * NN;
#pragma unroll
  for (int tt = 0; tt < 4; ++tt) {
    float bv = cn[BM2_C + tt * 16 + lo];
    f32x4 acc = {bv, bv, bv, bv};
    acc = __builtin_amdgcn_mfma_f32_16x16x32_bf16(h1a, w2f[tt][0], acc, 0, 0, 0);
    acc = __builtin_amdgcn_mfma_f32_16x16x32_bf16(h1b, w2f[tt][1], acc, 0, 0, 0);
    float v = fmaxf(fmaxf(lrelu(acc[0]), lrelu(acc[1])), fmaxf(lrelu(acc[2]), lrelu(acc[3])));
    v = fmaxf(v, __shfl_xor(v, 16, 64));
    v = fmaxf(v, __shfl_xor(v, 32, 64));
    if (g == 0) out[obase + (size_t)(tt * 16 + lo) * NN + q] = v;
  }
}

// workspace layout (float units)
#define CN_OFF 0
#define FB_OFF ((size_t)CN_TOTAL)                      // 2,163,200
#define KT_OFF (FB_OFF + (size_t)4 * BB * NN * CH)     // fbuf 2,097,152
#define XZ_OFF (KT_OFF + (size_t)2 * BB * NN * CH)     // knnt 2,097,152
#define WP4_OFF (XZ_OFF + (size_t)2 * BB * NN * 4)     // xyzt 65,536
#define WMB_OFF (WP4_OFF + 256)                        // 8192 bf16 = 4096 floats
#define IDX_OFF (WMB_OFF + 4096)                       // 262,144 ints
#define FLAG_OFF (IDX_OFF + 262144)                    // 1 int (+pad)
#define KNB_OFF (FLAG_OFF + 4)                         // 2,097,152 bf16 = 1,048,576 floats

extern "C" void kernel_launch(void* const* d_in, const int* in_sizes, int n_in,
                              void* d_out, int out_size, void* d_ws, size_t ws_size,
                              hipStream_t stream) {
  float* ws = (float*)d_ws;
  float* cn = ws + CN_OFF;
  int* flag = (int*)(ws + FLAG_OFF);

  k_detect<<<1, 64, 0, stream>>>((const unsigned short*)d_in[0], flag);
  k_ingest<<<(CN_TOTAL + 255) / 256, 256, 0, stream>>>(
      d_in[0], d_in[1], d_in[2], d_in[3], d_in[4], d_in[5], d_in[6], d_in[7],
      d_in[8], d_in[9], d_in[10], d_in[11], d_in[12], d_in[13], d_in[14], d_in[15],
      flag, cn);
  k_prep_misc<<<97, 256, 0, stream>>>(cn, (__hip_bfloat16*)(ws + WMB_OFF),
                                      (float4*)(ws + XZ_OFF), (float4*)(ws + WP4_OFF));
  k_prep_knn<<<(2 * BB * NN) / 256, 256, 0, stream>>>(cn, ws + KT_OFF,
                                                     (__hip_bfloat16*)(ws + KNB_OFF));
  k_conv<<<4 * BB * (NN / 4), 256, 0, stream>>>(cn, ws + FB_OFF);
  k_knn3<<<2 * BB * (NN / 16), 512, 0, stream>>>(
      (const __hip_bfloat16*)(ws + KNB_OFF), ws + KT_OFF,
      (const float4*)(ws + XZ_OFF), (int*)(ws + IDX_OFF));
  k_mlp<<<2 * BB * (NN / 4), 256, 0, stream>>>(ws + FB_OFF, (const float4*)(ws + XZ_OFF),
                                               (const int*)(ws + IDX_OFF), (const float4*)(ws + WP4_OFF),
                                               (const __hip_bfloat16*)(ws + WMB_OFF), cn,
                                               (float*)d_out);
}

// Round 5
// 304.446 us; speedup vs baseline: 2.7536x; 1.0239x over previous
//
#include <hip/hip_runtime.h>
#include <hip/hip_bf16.h>

#define BB 2
#define NN 4096
#define CH 64

typedef __bf16 bf16x8 __attribute__((ext_vector_type(8)));
typedef float f32x4 __attribute__((ext_vector_type(4)));

__device__ __forceinline__ float lrelu(float v) { return fmaxf(v, 0.1f * v); }
__device__ __forceinline__ float tobf(const __hip_bfloat16& h) { return __bfloat162float(h); }

// canonical f32 input region offsets (element offsets within cn)
#define PC1_C 0
#define PC2_C 24576
#define F1_C 49152
#define F2_C 573440
#define K1_C 1097728
#define K2_C 1622016
#define WT11_C 2146304
#define BT11_C 2150400
#define WT22_C 2150464
#define BT22_C 2154560
#define WPOS_C 2154624
#define BPOS_C 2154816
#define WM1_C 2154880
#define BM1_C 2158976
#define WM2_C 2159040
#define BM2_C 2163136
#define CN_TOTAL 2163200

// ---- packed selection keys: (order-mapped f32 score, top 20 bits)<<12 | (4095-idx)
__device__ __forceinline__ unsigned fmap(float s) {
  unsigned u = __float_as_uint(s);
  return u ^ ((unsigned)((int)u >> 31) | 0x80000000u);
}

__device__ __forceinline__ unsigned umaxu(unsigned a, unsigned b) { return a > b ? a : b; }
__device__ __forceinline__ void casu(unsigned& a, unsigned& b) {
  unsigned mx = a > b ? a : b;
  unsigned mn = a > b ? b : a;
  a = mx; b = mn;
}

// bitonic-8 desc merge (input bitonic -> sorted desc)
__device__ __forceinline__ void bitonic8(unsigned bd[8]) {
  casu(bd[0], bd[4]); casu(bd[1], bd[5]); casu(bd[2], bd[6]); casu(bd[3], bd[7]);
  casu(bd[0], bd[2]); casu(bd[1], bd[3]); casu(bd[4], bd[6]); casu(bd[5], bd[7]);
  casu(bd[0], bd[1]); casu(bd[2], bd[3]); casu(bd[4], bd[5]); casu(bd[6], bd[7]);
}

// merge 4 new keys into sorted-desc-8 bd[] (branch-free)
__device__ __forceinline__ void merge4(unsigned bd[8], unsigned k0, unsigned k1,
                                       unsigned k2, unsigned k3) {
  casu(k0, k1); casu(k2, k3); casu(k0, k2); casu(k1, k3); casu(k1, k2);
  bd[4] = umaxu(bd[4], k3); bd[5] = umaxu(bd[5], k2);
  bd[6] = umaxu(bd[6], k1); bd[7] = umaxu(bd[7], k0);
  bitonic8(bd);
}

// top-8 of union of two sorted-desc-8 lists -> a[]
__device__ __forceinline__ void merge88(unsigned a[8], const unsigned b[8]) {
  a[0] = umaxu(a[0], b[7]); a[1] = umaxu(a[1], b[6]);
  a[2] = umaxu(a[2], b[5]); a[3] = umaxu(a[3], b[4]);
  a[4] = umaxu(a[4], b[3]); a[5] = umaxu(a[5], b[2]);
  a[6] = umaxu(a[6], b[1]); a[7] = umaxu(a[7], b[0]);
  bitonic8(a);
}

// ---- dtype detector
__global__ void k_detect(const unsigned short* __restrict__ pc1raw, int* __restrict__ flag) {
  int lane = threadIdx.x;  // 64
  int bad = 0;
#pragma unroll
  for (int i = 0; i < 64; ++i) {
    unsigned short u = pc1raw[lane * 64 + i];
    int e = (u >> 7) & 0xFF;
    bad += (e >= 140) ? 1 : 0;  // |v| >= 2^13 or Inf/NaN
  }
#pragma unroll
  for (int s = 32; s; s >>= 1) bad += __shfl_xor(bad, s, 64);
  if (lane == 0) *flag = (bad > 16) ? 1 : 0;  // 1 = inputs are float32
}

// ---- ingest: convert all 16 inputs to canonical f32 + sanitize
__global__ __launch_bounds__(256) void k_ingest(
    const void* p0, const void* p1, const void* p2, const void* p3,
    const void* p4, const void* p5, const void* p6, const void* p7,
    const void* p8, const void* p9, const void* p10, const void* p11,
    const void* p12, const void* p13, const void* p14, const void* p15,
    const int* __restrict__ flag, float* __restrict__ dst) {
  const int cum[17] = {0, 24576, 49152, 573440, 1097728, 1622016, 2146304, 2150400,
                       2150464, 2154560, 2154624, 2154816, 2154880, 2158976, 2159040,
                       2163136, 2163200};
  size_t t = (size_t)blockIdx.x * 256 + threadIdx.x;
  if (t >= (size_t)CN_TOTAL) return;
  int seg = 0;
#pragma unroll
  for (int i = 1; i < 16; ++i) seg += (t >= (size_t)cum[i]) ? 1 : 0;
  size_t local = t - (size_t)cum[seg];
  const void* ptrs[16] = {p0, p1, p2, p3, p4, p5, p6, p7, p8, p9, p10, p11, p12, p13, p14, p15};
  const void* p = ptrs[seg];
  float v;
  if (*flag) v = ((const float*)p)[local];
  else       v = tobf(((const __hip_bfloat16*)p)[local]);
  if (!(v == v) || fabsf(v) > 1e30f) v = 0.f;  // sanitize (no-op on clean data)
  dst[t] = v;
}

// ---- fused misc prep: blocks 0..31 Wm->bf16, 32..95 xyz float4, 96 wpos
__global__ __launch_bounds__(256) void k_prep_misc(const float* __restrict__ cn,
                                                   __hip_bfloat16* __restrict__ wmb,
                                                   float4* __restrict__ xyzt,
                                                   float4* __restrict__ wp4) {
  int bid = blockIdx.x;
  if (bid < 32) {
    int t = bid * 256 + threadIdx.x;  // 8192
    float v = (t < 4096) ? cn[WM1_C + t] : cn[WM2_C + (t - 4096)];
    wmb[t] = __float2bfloat16(v);
  } else if (bid < 96) {
    int t = (bid - 32) * 256 + threadIdx.x;  // 2*BB*NN = 16384
    int n = t & (NN - 1);
    int b = (t >> 12) & 1;
    int a = t >> 13;
    const float* p = cn + (a ? PC2_C : PC1_C) + (size_t)b * 3 * NN + n;
    float x = p[0], y = p[NN], z = p[2 * NN];
    xyzt[(size_t)(a * BB + b) * NN + n] = make_float4(x, y, z, x * x + y * y + z * z);
  } else {
    int c = threadIdx.x;
    if (c < 64)
      wp4[c] = make_float4(cn[WPOS_C + 3 * c], cn[WPOS_C + 3 * c + 1],
                           cn[WPOS_C + 3 * c + 2], cn[BPOS_C + c]);
  }
}

// ---- prep: knn [B,64,N] f32 -> row-normalized f32 [2][B][N][64] + bf16 copy
__global__ __launch_bounds__(256) void k_prep_knn(const float* __restrict__ cn,
                                                  float* __restrict__ knnt,
                                                  __hip_bfloat16* __restrict__ knnb) {
  int t = blockIdx.x * 256 + threadIdx.x;  // 2*BB*NN
  int n = t & (NN - 1);
  int b = (t >> 12) & 1;
  int a = t >> 13;
  const float* col = cn + (a ? K2_C : K1_C) + (size_t)b * CH * NN + n;
  float s = 0.f;
#pragma unroll
  for (int c = 0; c < CH; ++c) { float v = col[(size_t)c * NN]; s += v * v; }
  float inv = 1.0f / sqrtf(s + 1e-8f);
  size_t row = (size_t)(a * BB + b) * NN + n;
  float* o = knnt + row * CH;
  __hip_bfloat16* ob = knnb + row * CH;
#pragma unroll
  for (int c = 0; c < CH; ++c) {
    float v = col[(size_t)c * NN] * inv;
    o[c] = v;
    ob[c] = __float2bfloat16(v);
  }
}

// ---- 1x1 convs
__global__ __launch_bounds__(256) void k_conv(const float* __restrict__ cn,
                                              float* __restrict__ fbuf) {
  __shared__ float wl[CH * CH];  // [c][d]
  int bid = blockIdx.x;          // 4*BB*(NN/4)
  int tile = bid & (NN / 4 - 1);
  int b = (bid >> 10) & 1;
  int sel = bid >> 11;
  const float* W = cn + ((sel == 0 || sel == 2) ? WT11_C : WT22_C);
  const float* bias = cn + ((sel == 0 || sel == 2) ? BT11_C : BT22_C);
  const float* feat = cn + ((sel == 0 || sel == 3) ? F1_C : F2_C);
  int t = threadIdx.x;
#pragma unroll
  for (int i = 0; i < 16; ++i) {
    int e = t * 16 + i;  // W[d][c] row-major -> wl[c][d]
    wl[(e & 63) * 64 + (e >> 6)] = W[e];
  }
  __syncthreads();
  int p = t >> 6, d = t & 63;
  int n = tile * 4 + p;
  const float* fc = feat + (size_t)b * CH * NN + n;
  float acc = bias[d];
#pragma unroll
  for (int c = 0; c < CH; ++c) acc += wl[c * 64 + d] * fc[(size_t)c * NN];
  fbuf[((size_t)(sel * BB + b) * NN + n) * CH + d] = acc;
}

// ======================================================================
// R9 k_knn4 (resubmit; R4's run was an infra failure, no counters):
// (1) software-pipelined scan -- A/B ping-pong register prefetch issues
// tile t+1's 6 loads before computing tile t, hiding ~200cy L2 latency
// (R8 evidence: VALUBusy 60->49, dur flat == latency-bound);
// (2) extraction's 8-round argmax (40 dependent shfls) replaced by one
// 15-stage bitonic sort across 32 lanes on (f32 val, idx-asc).
// ======================================================================
__global__ __launch_bounds__(512, 4) void k_knn4(const __hip_bfloat16* __restrict__ knnb,
                                                 const float* __restrict__ knnt,
                                                 const float4* __restrict__ xyzt,
                                                 int* __restrict__ idxf) {
  __shared__ unsigned sk[16 * 8 * 33];  // 16.9 KB, reused cos -> euclid
  __shared__ int cidx[16 * 16];
  int bid = blockIdx.x;  // 2*BB*(NN/16) = 1024 : x(1) | b(1) | qt(8)
  int qt = bid & (NN / 16 - 1);
  int b = (bid >> 8) & 1;
  int x = bid >> 9;
  int w = threadIdx.x >> 6;
  int lane = threadIdx.x & 63;
  int lo = lane & 15, g = lane >> 4;
  int q0 = qt * 16;
  int j0 = w * (NN / 8);
  int ss = w * 4 + g;
  int hw = lane >> 5, sl = lane & 31;
  int qq = w * 2 + hw;  // extraction query (0..15)
  size_t qbase = (size_t)(x * BB + b) * NN;
  size_t dbase = (size_t)((1 - x) * BB + b) * NN;

  // resident query data
  const __hip_bfloat16* qb = knnb + (qbase + q0) * CH;
  bf16x8 qf0 = *reinterpret_cast<const bf16x8*>(qb + lo * CH + g * 8);
  bf16x8 qf1 = *reinterpret_cast<const bf16x8*>(qb + lo * CH + 32 + g * 8);
  const __hip_bfloat16* db = knnb + dbase * CH;
  const float4 q4 = xyzt[qbase + q0 + lo];
  const float4* dbx = xyzt + dbase;
  float tx = 2.f * q4.x, ty = 2.f * q4.y, tz = 2.f * q4.z;

  unsigned bc0[8], bc1[8], be0[8], be1[8];
#pragma unroll
  for (int k = 0; k < 8; ++k) { bc0[k] = 0u; bc1[k] = 0u; be0[k] = 0u; be1[k] = 0u; }

  auto STEP = [&](const bf16x8& A0, const bf16x8& A1, const float4& P0,
                  const float4& P1, const float4& P2, const float4& P3,
                  int rcv, unsigned (&bc)[8], unsigned (&be)[8]) {
    f32x4 acc = {0.f, 0.f, 0.f, 0.f};
    acc = __builtin_amdgcn_mfma_f32_16x16x32_bf16(A0, qf0, acc, 0, 0, 0);
    acc = __builtin_amdgcn_mfma_f32_16x16x32_bf16(A1, qf1, acc, 0, 0, 0);
    float v0 = fmaf(tx, P0.x, fmaf(ty, P0.y, fmaf(tz, P0.z, -P0.w)));
    float v1 = fmaf(tx, P1.x, fmaf(ty, P1.y, fmaf(tz, P1.z, -P1.w)));
    float v2 = fmaf(tx, P2.x, fmaf(ty, P2.y, fmaf(tz, P2.z, -P2.w)));
    float v3 = fmaf(tx, P3.x, fmaf(ty, P3.y, fmaf(tz, P3.z, -P3.w)));
    unsigned r = (unsigned)rcv;
    merge4(bc, (__float_as_uint(acc[0] + 4.0f) & 0xFFFFF000u) | r,
               (__float_as_uint(acc[1] + 4.0f) & 0xFFFFF000u) | (r - 1),
               (__float_as_uint(acc[2] + 4.0f) & 0xFFFFF000u) | (r - 2),
               (__float_as_uint(acc[3] + 4.0f) & 0xFFFFF000u) | (r - 3));
    merge4(be, (fmap(v0) & 0xFFFFF000u) | r,
               (fmap(v1) & 0xFFFFF000u) | (r - 1),
               (fmap(v2) & 0xFFFFF000u) | (r - 2),
               (fmap(v3) & 0xFFFFF000u) | (r - 3));
  };

  // ---- pipelined scan: 32 tiles, A=even / B=odd, one-tile prefetch ahead
  const __hip_bfloat16* arA = db + (size_t)(j0 + lo) * CH + g * 8;
  const __hip_bfloat16* arB = arA + 16 * CH;
  const float4* peA = dbx + j0 + g * 4;
  const float4* peB = peA + 16;
  int rc = 4095 - j0 - g * 4;

  bf16x8 aA0 = *reinterpret_cast<const bf16x8*>(arA);
  bf16x8 aA1 = *reinterpret_cast<const bf16x8*>(arA + 32);
  float4 pA0 = peA[0], pA1 = peA[1], pA2 = peA[2], pA3 = peA[3];

  for (int i = 0; i < 15; ++i) {
    bf16x8 aB0 = *reinterpret_cast<const bf16x8*>(arB);
    bf16x8 aB1 = *reinterpret_cast<const bf16x8*>(arB + 32);
    float4 pB0 = peB[0], pB1 = peB[1], pB2 = peB[2], pB3 = peB[3];
    STEP(aA0, aA1, pA0, pA1, pA2, pA3, rc, bc0, be0);
    arA += 32 * CH; peA += 32;
    aA0 = *reinterpret_cast<const bf16x8*>(arA);
    aA1 = *reinterpret_cast<const bf16x8*>(arA + 32);
    pA0 = peA[0]; pA1 = peA[1]; pA2 = peA[2]; pA3 = peA[3];
    STEP(aB0, aB1, pB0, pB1, pB2, pB3, rc - 16, bc1, be1);
    arB += 32 * CH; peB += 32;
    rc -= 32;
  }
  {
    bf16x8 aB0 = *reinterpret_cast<const bf16x8*>(arB);
    bf16x8 aB1 = *reinterpret_cast<const bf16x8*>(arB + 32);
    float4 pB0 = peB[0], pB1 = peB[1], pB2 = peB[2], pB3 = peB[3];
    STEP(aA0, aA1, pA0, pA1, pA2, pA3, rc, bc0, be0);
    STEP(aB0, aB1, pB0, pB1, pB2, pB3, rc - 16, bc1, be1);
  }
  merge88(bc0, bc1);
  merge88(be0, be1);

  // ================= cosine extraction =================
#pragma unroll
  for (int k = 0; k < 8; ++k) sk[(lo * 8 + k) * 33 + ss] = bc0[k];
  __syncthreads();
  {
    unsigned e[16];
#pragma unroll
    for (int k = 0; k < 8; ++k) e[k] = sk[(qq * 8 + k) * 33 + sl];
#pragma unroll
    for (int k = 8; k < 16; ++k) e[k] = 0u;
#pragma unroll
    for (int s = 1; s < 32; s <<= 1) {
      unsigned f[16];
#pragma unroll
      for (int k = 0; k < 16; ++k) f[k] = (unsigned)__shfl_xor((int)e[k], s, 64);
#pragma unroll
      for (int i = 0; i < 16; ++i) e[i] = umaxu(e[i], f[15 - i]);
      casu(e[0], e[8]); casu(e[1], e[9]); casu(e[2], e[10]); casu(e[3], e[11]);
      casu(e[4], e[12]); casu(e[5], e[13]); casu(e[6], e[14]); casu(e[7], e[15]);
      casu(e[0], e[4]); casu(e[1], e[5]); casu(e[2], e[6]); casu(e[3], e[7]);
      casu(e[8], e[12]); casu(e[9], e[13]); casu(e[10], e[14]); casu(e[11], e[15]);
      casu(e[0], e[2]); casu(e[1], e[3]); casu(e[4], e[6]); casu(e[5], e[7]);
      casu(e[8], e[10]); casu(e[9], e[11]); casu(e[12], e[14]); casu(e[13], e[15]);
      casu(e[0], e[1]); casu(e[2], e[3]); casu(e[4], e[5]); casu(e[6], e[7]);
      casu(e[8], e[9]); casu(e[10], e[11]); casu(e[12], e[13]); casu(e[14], e[15]);
    }
    if (sl == 0) {
#pragma unroll
      for (int k = 0; k < 16; ++k) cidx[qq * 16 + k] = 4095 - (int)(e[k] & 4095u);
    }
    int c = sl >> 1, hr = sl & 1;
    int idx = cidx[qq * 16 + c];
    const float4* qr = reinterpret_cast<const float4*>(knnt + (qbase + q0 + qq) * CH) + hr * 8;
    const float4* dr = reinterpret_cast<const float4*>(knnt + (dbase + idx) * CH) + hr * 8;
    float v = 0.f;
#pragma unroll 4
    for (int cb = 0; cb < 8; ++cb) {
      float4 qv = qr[cb], dv = dr[cb];
      v += qv.x * dv.x + qv.y * dv.y + qv.z * dv.z + qv.w * dv.w;
    }
    v += __shfl_xor(v, 1, 64);  // combine halves (bitwise identical across pair)
    int ii = idx;
#pragma unroll
    for (int k = 2; k <= 32; k <<= 1) {
#pragma unroll
      for (int j = k >> 1; j >= 1; j >>= 1) {
        float ov = __shfl_xor(v, j, 64);
        int oi = __shfl_xor(ii, j, 64);
        bool ob = (ov > v) || (ov == v && oi < ii);
        bool want = (((sl & k) == 0) == ((sl & j) == 0));
        bool take = (want == ob);
        v = take ? ov : v;
        ii = take ? oi : ii;
      }
    }
    if (sl < 16 && (sl & 1) == 0) idxf[(qbase + q0 + qq) * 16 + (sl >> 1)] = ii;
  }
  __syncthreads();

  // ================= euclid extraction =================
#pragma unroll
  for (int k = 0; k < 8; ++k) sk[(lo * 8 + k) * 33 + ss] = be0[k];
  __syncthreads();
  {
    unsigned e[16];
#pragma unroll
    for (int k = 0; k < 8; ++k) e[k] = sk[(qq * 8 + k) * 33 + sl];
#pragma unroll
    for (int k = 8; k < 16; ++k) e[k] = 0u;
#pragma unroll
    for (int s = 1; s < 32; s <<= 1) {
      unsigned f[16];
#pragma unroll
      for (int k = 0; k < 16; ++k) f[k] = (unsigned)__shfl_xor((int)e[k], s, 64);
#pragma unroll
      for (int i = 0; i < 16; ++i) e[i] = umaxu(e[i], f[15 - i]);
      casu(e[0], e[8]); casu(e[1], e[9]); casu(e[2], e[10]); casu(e[3], e[11]);
      casu(e[4], e[12]); casu(e[5], e[13]); casu(e[6], e[14]); casu(e[7], e[15]);
      casu(e[0], e[4]); casu(e[1], e[5]); casu(e[2], e[6]); casu(e[3], e[7]);
      casu(e[8], e[12]); casu(e[9], e[13]); casu(e[10], e[14]); casu(e[11], e[15]);
      casu(e[0], e[2]); casu(e[1], e[3]); casu(e[4], e[6]); casu(e[5], e[7]);
      casu(e[8], e[10]); casu(e[9], e[11]); casu(e[12], e[14]); casu(e[13], e[15]);
      casu(e[0], e[1]); casu(e[2], e[3]); casu(e[4], e[5]); casu(e[6], e[7]);
      casu(e[8], e[9]); casu(e[10], e[11]); casu(e[12], e[13]); casu(e[14], e[15]);
    }
    if (sl == 0) {
#pragma unroll
      for (int k = 0; k < 16; ++k) cidx[qq * 16 + k] = 4095 - (int)(e[k] & 4095u);
    }
    int c = sl >> 1;
    int idx = cidx[qq * 16 + c];
    const float4 qx4 = xyzt[qbase + q0 + qq];
    float4 p = xyzt[dbase + idx];
    float v = fmaf(2.f * qx4.x, p.x, fmaf(2.f * qx4.y, p.y, fmaf(2.f * qx4.z, p.z, -p.w)));
    int ii = idx;
#pragma unroll
    for (int k = 2; k <= 32; k <<= 1) {
#pragma unroll
      for (int j = k >> 1; j >= 1; j >>= 1) {
        float ov = __shfl_xor(v, j, 64);
        int oi = __shfl_xor(ii, j, 64);
        bool ob = (ov > v) || (ov == v && oi < ii);
        bool want = (((sl & k) == 0) == ((sl & j) == 0));
        bool take = (want == ob);
        v = take ? ov : v;
        ii = take ? oi : ii;
      }
    }
    if (sl < 16 && (sl & 1) == 0) idxf[(qbase + q0 + qq) * 16 + 8 + (sl >> 1)] = ii;
  }
}

// ---- fused gather + pos-conv + 2x MFMA MLP + neighbor max. One wave per query.
__global__ __launch_bounds__(256) void k_mlp(const float* __restrict__ fbuf,
                                             const float4* __restrict__ xyzt,
                                             const int* __restrict__ idxf,
                                             const float4* __restrict__ wp4,
                                             const __hip_bfloat16* __restrict__ wmb,
                                             const float* __restrict__ cn,
                                             float* __restrict__ out) {
  __shared__ __bf16 h1s[4 * 16 * 72];  // per-wave 16 rows x stride 72
  const int t = threadIdx.x;
  const int wv = t >> 6, L = t & 63;
  const int lo = L & 15, g = L >> 4;
  int bid = blockIdx.x;  // 2*BB*(NN/4) = 4096
  const int qt = bid & (NN / 4 - 1);
  const int b = (bid >> 10) & 1;
  const int x = bid >> 11;
  const int q = qt * 4 + wv;

  bf16x8 w1f[4][2], w2f[4][2];
#pragma unroll
  for (int tt = 0; tt < 4; ++tt)
#pragma unroll
    for (int kc = 0; kc < 2; ++kc) {
      int e = tt * 16 + lo, c0 = kc * 32 + g * 8;
      w1f[tt][kc] = *reinterpret_cast<const bf16x8*>(wmb + e * 64 + c0);
      w2f[tt][kc] = *reinterpret_cast<const bf16x8*>(wmb + 4096 + e * 64 + c0);
    }

  const float* pq  = fbuf + ((size_t)((x ? 2 : 0) * BB + b)) * NN * CH;
  const float* pdb = fbuf + ((size_t)((x ? 3 : 1) * BB + b)) * NN * CH;
  const float4* qx  = xyzt + (size_t)(x * BB + b) * NN;
  const float4* dbx = xyzt + (size_t)((1 - x) * BB + b) * NN;

  const int m = lo;
  int jm = idxf[(((size_t)x * BB + b) * NN + q) * 16 + m];
  jm &= (NN - 1);
  const float4 q4 = qx[q];
  const float4 p4 = dbx[jm];
  const float dx = p4.x - q4.x, dy = p4.y - q4.y, dz = p4.z - q4.z;

  const float4* g2v = reinterpret_cast<const float4*>(pdb + (size_t)jm * CH);
  const float4* pqv = reinterpret_cast<const float4*>(pq + (size_t)q * CH);
  float hv[16];
  {
    float4 t0 = g2v[g * 2], t1 = g2v[g * 2 + 1], t2 = g2v[g * 2 + 8], t3 = g2v[g * 2 + 9];
    float4 u0 = pqv[g * 2], u1 = pqv[g * 2 + 1], u2 = pqv[g * 2 + 8], u3 = pqv[g * 2 + 9];
    hv[0] = t0.x + u0.x; hv[1] = t0.y + u0.y; hv[2] = t0.z + u0.z; hv[3] = t0.w + u0.w;
    hv[4] = t1.x + u1.x; hv[5] = t1.y + u1.y; hv[6] = t1.z + u1.z; hv[7] = t1.w + u1.w;
    hv[8] = t2.x + u2.x; hv[9] = t2.y + u2.y; hv[10] = t2.z + u2.z; hv[11] = t2.w + u2.w;
    hv[12] = t3.x + u3.x; hv[13] = t3.y + u3.y; hv[14] = t3.z + u3.z; hv[15] = t3.w + u3.w;
  }

  bf16x8 a0, a1;
#pragma unroll
  for (int kc = 0; kc < 2; ++kc) {
#pragma unroll
    for (int j = 0; j < 8; ++j) {
      int c = kc * 32 + g * 8 + j;
      float4 wp = wp4[c];
      float v = hv[kc * 8 + j] + wp.x * dx + wp.y * dy + wp.z * dz + wp.w;
      v = lrelu(v);
      if (kc == 0) a0[j] = (__bf16)v; else a1[j] = (__bf16)v;
    }
  }

  __bf16* hrow = h1s + wv * 16 * 72;
#pragma unroll
  for (int tt = 0; tt < 4; ++tt) {
    float bv = cn[BM1_C + tt * 16 + lo];
    f32x4 acc = {bv, bv, bv, bv};
    acc = __builtin_amdgcn_mfma_f32_16x16x32_bf16(a0, w1f[tt][0], acc, 0, 0, 0);
    acc = __builtin_amdgcn_mfma_f32_16x16x32_bf16(a1, w1f[tt][1], acc, 0, 0, 0);
#pragma unroll
    for (int r = 0; r < 4; ++r) {
      float v = lrelu(acc[r]);
      hrow[(g * 4 + r) * 72 + tt * 16 + lo] = (__bf16)v;
    }
  }
  __syncthreads();
  bf16x8 h1a = *reinterpret_cast<const bf16x8*>(hrow + m * 72 + g * 8);
  bf16x8 h1b = *reinterpret_cast<const bf16x8*>(hrow + m * 72 + 32 + g * 8);

  size_t obase = ((size_t)(x * BB + b) * CH) * NN;
#pragma unroll
  for (int tt = 0; tt < 4; ++tt) {
    float bv = cn[BM2_C + tt * 16 + lo];
    f32x4 acc = {bv, bv, bv, bv};
    acc = __builtin_amdgcn_mfma_f32_16x16x32_bf16(h1a, w2f[tt][0], acc, 0, 0, 0);
    acc = __builtin_amdgcn_mfma_f32_16x16x32_bf16(h1b, w2f[tt][1], acc, 0, 0, 0);
    float v = fmaxf(fmaxf(lrelu(acc[0]), lrelu(acc[1])), fmaxf(lrelu(acc[2]), lrelu(acc[3])));
    v = fmaxf(v, __shfl_xor(v, 16, 64));
    v = fmaxf(v, __shfl_xor(v, 32, 64));
    if (g == 0) out[obase + (size_t)(tt * 16 + lo) * NN + q] = v;
  }
}

// workspace layout (float units)
#define CN_OFF 0
#define FB_OFF ((size_t)CN_TOTAL)
#define KT_OFF (FB_OFF + (size_t)4 * BB * NN * CH)
#define XZ_OFF (KT_OFF + (size_t)2 * BB * NN * CH)
#define WP4_OFF (XZ_OFF + (size_t)2 * BB * NN * 4)
#define WMB_OFF (WP4_OFF + 256)
#define IDX_OFF (WMB_OFF + 4096)
#define FLAG_OFF (IDX_OFF + 262144)
#define KNB_OFF (FLAG_OFF + 4)

extern "C" void kernel_launch(void* const* d_in, const int* in_sizes, int n_in,
                              void* d_out, int out_size, void* d_ws, size_t ws_size,
                              hipStream_t stream) {
  float* ws = (float*)d_ws;
  float* cn = ws + CN_OFF;
  int* flag = (int*)(ws + FLAG_OFF);

  k_detect<<<1, 64, 0, stream>>>((const unsigned short*)d_in[0], flag);
  k_ingest<<<(CN_TOTAL + 255) / 256, 256, 0, stream>>>(
      d_in[0], d_in[1], d_in[2], d_in[3], d_in[4], d_in[5], d_in[6], d_in[7],
      d_in[8], d_in[9], d_in[10], d_in[11], d_in[12], d_in[13], d_in[14], d_in[15],
      flag, cn);
  k_prep_misc<<<97, 256, 0, stream>>>(cn, (__hip_bfloat16*)(ws + WMB_OFF),
                                      (float4*)(ws + XZ_OFF), (float4*)(ws + WP4_OFF));
  k_prep_knn<<<(2 * BB * NN) / 256, 256, 0, stream>>>(cn, ws + KT_OFF,
                                                     (__hip_bfloat16*)(ws + KNB_OFF));
  k_conv<<<4 * BB * (NN / 4), 256, 0, stream>>>(cn, ws + FB_OFF);
  k_knn4<<<2 * BB * (NN / 16), 512, 0, stream>>>(
      (const __hip_bfloat16*)(ws + KNB_OFF), ws + KT_OFF,
      (const float4*)(ws + XZ_OFF), (int*)(ws + IDX_OFF));
  k_mlp<<<2 * BB * (NN / 4), 256, 0, stream>>>(ws + FB_OFF, (const float4*)(ws + XZ_OFF),
                                               (const int*)(ws + IDX_OFF), (const float4*)(ws + WP4_OFF),
                                               (const __hip_bfloat16*)(ws + WMB_OFF), cn,
                                               (float*)d_out);
}

// Round 6
// 295.521 us; speedup vs baseline: 2.8368x; 1.0302x over previous
//
#include <hip/hip_runtime.h>
#include <hip/hip_bf16.h>

#define BB 2
#define NN 4096
#define CH 64

typedef __bf16 bf16x8 __attribute__((ext_vector_type(8)));
typedef float f32x4 __attribute__((ext_vector_type(4)));

__device__ __forceinline__ float lrelu(float v) { return fmaxf(v, 0.1f * v); }
__device__ __forceinline__ float tobf(const __hip_bfloat16& h) { return __bfloat162float(h); }

// canonical f32 input region offsets (element offsets within cn)
#define PC1_C 0
#define PC2_C 24576
#define F1_C 49152
#define F2_C 573440
#define K1_C 1097728
#define K2_C 1622016
#define WT11_C 2146304
#define BT11_C 2150400
#define WT22_C 2150464
#define BT22_C 2154560
#define WPOS_C 2154624
#define BPOS_C 2154816
#define WM1_C 2154880
#define BM1_C 2158976
#define WM2_C 2159040
#define BM2_C 2163136
#define CN_TOTAL 2163200

// fhl half offset (bf16 elements): fl mirror of fh
#define FHALF (2 * BB * NN * CH)

// ---- packed selection keys: (order-mapped f32 score, top 20 bits)<<12 | (4095-idx)
__device__ __forceinline__ unsigned fmap(float s) {
  unsigned u = __float_as_uint(s);
  return u ^ ((unsigned)((int)u >> 31) | 0x80000000u);
}

__device__ __forceinline__ unsigned umaxu(unsigned a, unsigned b) { return a > b ? a : b; }
__device__ __forceinline__ void casu(unsigned& a, unsigned& b) {
  unsigned mx = a > b ? a : b;
  unsigned mn = a > b ? b : a;
  a = mx; b = mn;
}

// bitonic-8 desc merge (input bitonic -> sorted desc)
__device__ __forceinline__ void bitonic8(unsigned bd[8]) {
  casu(bd[0], bd[4]); casu(bd[1], bd[5]); casu(bd[2], bd[6]); casu(bd[3], bd[7]);
  casu(bd[0], bd[2]); casu(bd[1], bd[3]); casu(bd[4], bd[6]); casu(bd[5], bd[7]);
  casu(bd[0], bd[1]); casu(bd[2], bd[3]); casu(bd[4], bd[5]); casu(bd[6], bd[7]);
}

// merge 4 new keys into sorted-desc-8 bd[] (branch-free)
__device__ __forceinline__ void merge4(unsigned bd[8], unsigned k0, unsigned k1,
                                       unsigned k2, unsigned k3) {
  casu(k0, k1); casu(k2, k3); casu(k0, k2); casu(k1, k3); casu(k1, k2);
  bd[4] = umaxu(bd[4], k3); bd[5] = umaxu(bd[5], k2);
  bd[6] = umaxu(bd[6], k1); bd[7] = umaxu(bd[7], k0);
  bitonic8(bd);
}

// top-8 of union of two sorted-desc-8 lists -> a[]
__device__ __forceinline__ void merge88(unsigned a[8], const unsigned b[8]) {
  a[0] = umaxu(a[0], b[7]); a[1] = umaxu(a[1], b[6]);
  a[2] = umaxu(a[2], b[5]); a[3] = umaxu(a[3], b[4]);
  a[4] = umaxu(a[4], b[3]); a[5] = umaxu(a[5], b[2]);
  a[6] = umaxu(a[6], b[1]); a[7] = umaxu(a[7], b[0]);
  bitonic8(a);
}

// ---- dtype detector
__global__ void k_detect(const unsigned short* __restrict__ pc1raw, int* __restrict__ flag) {
  int lane = threadIdx.x;  // 64
  int bad = 0;
#pragma unroll
  for (int i = 0; i < 64; ++i) {
    unsigned short u = pc1raw[lane * 64 + i];
    int e = (u >> 7) & 0xFF;
    bad += (e >= 140) ? 1 : 0;  // |v| >= 2^13 or Inf/NaN
  }
#pragma unroll
  for (int s = 32; s; s >>= 1) bad += __shfl_xor(bad, s, 64);
  if (lane == 0) *flag = (bad > 16) ? 1 : 0;  // 1 = inputs are float32
}

// ---- ingest: convert all 16 inputs to canonical f32 + sanitize
__global__ __launch_bounds__(256) void k_ingest(
    const void* p0, const void* p1, const void* p2, const void* p3,
    const void* p4, const void* p5, const void* p6, const void* p7,
    const void* p8, const void* p9, const void* p10, const void* p11,
    const void* p12, const void* p13, const void* p14, const void* p15,
    const int* __restrict__ flag, float* __restrict__ dst) {
  const int cum[17] = {0, 24576, 49152, 573440, 1097728, 1622016, 2146304, 2150400,
                       2150464, 2154560, 2154624, 2154816, 2154880, 2158976, 2159040,
                       2163136, 2163200};
  size_t t = (size_t)blockIdx.x * 256 + threadIdx.x;
  if (t >= (size_t)CN_TOTAL) return;
  int seg = 0;
#pragma unroll
  for (int i = 1; i < 16; ++i) seg += (t >= (size_t)cum[i]) ? 1 : 0;
  size_t local = t - (size_t)cum[seg];
  const void* ptrs[16] = {p0, p1, p2, p3, p4, p5, p6, p7, p8, p9, p10, p11, p12, p13, p14, p15};
  const void* p = ptrs[seg];
  float v;
  if (*flag) v = ((const float*)p)[local];
  else       v = tobf(((const __hip_bfloat16*)p)[local]);
  if (!(v == v) || fabsf(v) > 1e30f) v = 0.f;  // sanitize (no-op on clean data)
  dst[t] = v;
}

// ---- fused misc prep: 0..31 Wm->bf16, 32..95 xyz float4, 96 wpos, 97..128 Wconv hi/lo
__global__ __launch_bounds__(256) void k_prep_misc(const float* __restrict__ cn,
                                                   __hip_bfloat16* __restrict__ wmb,
                                                   float4* __restrict__ xyzt,
                                                   float4* __restrict__ wp4,
                                                   __hip_bfloat16* __restrict__ wcb) {
  int bid = blockIdx.x;
  if (bid < 32) {
    int t = bid * 256 + threadIdx.x;  // 8192
    float v = (t < 4096) ? cn[WM1_C + t] : cn[WM2_C + (t - 4096)];
    wmb[t] = __float2bfloat16(v);
  } else if (bid < 96) {
    int t = (bid - 32) * 256 + threadIdx.x;  // 2*BB*NN = 16384
    int n = t & (NN - 1);
    int b = (t >> 12) & 1;
    int a = t >> 13;
    const float* p = cn + (a ? PC2_C : PC1_C) + (size_t)b * 3 * NN + n;
    float x = p[0], y = p[NN], z = p[2 * NN];
    xyzt[(size_t)(a * BB + b) * NN + n] = make_float4(x, y, z, x * x + y * y + z * z);
  } else if (bid == 96) {
    int c = threadIdx.x;
    if (c < 64)
      wp4[c] = make_float4(cn[WPOS_C + 3 * c], cn[WPOS_C + 3 * c + 1],
                           cn[WPOS_C + 3 * c + 2], cn[BPOS_C + c]);
  } else {
    // conv weight hi/lo split: wcb[w][d*64+c] hi at [0,8192), lo at [8192,16384)
    int t = (bid - 97) * 256 + threadIdx.x;  // 8192 = 2 W x 4096
    int w = t >> 12, e = t & 4095;
    float v = cn[(w ? WT22_C : WT11_C) + e];
    __hip_bfloat16 hi = __float2bfloat16(v);
    __hip_bfloat16 lo = __float2bfloat16(v - tobf(hi));
    wcb[w * 4096 + e] = hi;
    wcb[8192 + w * 4096 + e] = lo;
  }
}

// ---- prep: knn [B,64,N] f32 -> row-normalized f32 [2][B][N][64] + bf16 copy
__global__ __launch_bounds__(256) void k_prep_knn(const float* __restrict__ cn,
                                                  float* __restrict__ knnt,
                                                  __hip_bfloat16* __restrict__ knnb) {
  int t = blockIdx.x * 256 + threadIdx.x;  // 2*BB*NN
  int n = t & (NN - 1);
  int b = (t >> 12) & 1;
  int a = t >> 13;
  const float* col = cn + (a ? K2_C : K1_C) + (size_t)b * CH * NN + n;
  float s = 0.f;
#pragma unroll
  for (int c = 0; c < CH; ++c) { float v = col[(size_t)c * NN]; s += v * v; }
  float inv = 1.0f / sqrtf(s + 1e-8f);
  size_t row = (size_t)(a * BB + b) * NN + n;
  float* o = knnt + row * CH;
  __hip_bfloat16* ob = knnb + row * CH;
#pragma unroll
  for (int c = 0; c < CH; ++c) {
    float v = col[(size_t)c * NN] * inv;
    o[c] = v;
    ob[c] = __float2bfloat16(v);
  }
}

// ---- prep: feat [B,64,N] f32 -> [a][b][n][64] bf16 hi + lo (split precision)
__global__ __launch_bounds__(256) void k_prep_feat(const float* __restrict__ cn,
                                                   __hip_bfloat16* __restrict__ fhl) {
  int t = blockIdx.x * 256 + threadIdx.x;  // 2*BB*NN = 16384
  int n = t & (NN - 1);
  int b = (t >> 12) & 1;
  int a = t >> 13;
  const float* col = cn + (a ? F2_C : F1_C) + (size_t)b * CH * NN + n;
  __hip_bfloat16* oh = fhl + ((size_t)(a * BB + b) * NN + n) * CH;
  __hip_bfloat16* ol = oh + FHALF;
#pragma unroll
  for (int c = 0; c < CH; ++c) {
    float v = col[(size_t)c * NN];
    __hip_bfloat16 hi = __float2bfloat16(v);
    oh[c] = hi;
    ol[c] = __float2bfloat16(v - tobf(hi));
  }
}

// ======================================================================
// R10 k_conv2: the old k_conv was an 8.6-GFLOP f32 GEMM on the VALU
// (floor ~55us at 157TF peak). Move it to the matrix pipe via bf16
// hi/lo split: w.f = wh.fh + wh.fl + wl.fh (+wl.fl dropped, <=2^-18 rel)
// -> error ~3e-5, far below downstream bf16-H0 quantization (4e-3).
// Layout mirrors proven k_mlp fragments: A[m=n][k=c], B[n=d][k=c],
// D col(lane&15)=d, row(g*4+r)=n. 1024 blocks x 4 waves (wave = d-tile),
// each wave computes 16n x 16d for BOTH weights (A-frags amortized).
// sel: 0=(W11,f1) 1=(W22,f2) 2=(W11,f2) 3=(W22,f1).
// ======================================================================
__global__ __launch_bounds__(256) void k_conv2(const __hip_bfloat16* __restrict__ fhl,
                                               const __hip_bfloat16* __restrict__ wcb,
                                               const float* __restrict__ cn,
                                               float* __restrict__ fbuf) {
  int bid = blockIdx.x;  // 1024: ntile(8b) | b(1) | a(1)
  int ntile = bid & 255;
  int b = (bid >> 8) & 1;
  int a = bid >> 9;
  int t = threadIdx.x;
  int dt = t >> 6;  // wave = d-tile (0..3)
  int lane = t & 63;
  int lo = lane & 15, g = lane >> 4;

  // A-frags: row n = ntile*16+lo, channels kc*32 + g*8 .. +7 (hi and lo parts)
  const __hip_bfloat16* fb = fhl + ((size_t)(a * BB + b) * NN + ntile * 16 + lo) * CH;
  bf16x8 ah0 = *reinterpret_cast<const bf16x8*>(fb + g * 8);
  bf16x8 ah1 = *reinterpret_cast<const bf16x8*>(fb + 32 + g * 8);
  bf16x8 al0 = *reinterpret_cast<const bf16x8*>(fb + FHALF + g * 8);
  bf16x8 al1 = *reinterpret_cast<const bf16x8*>(fb + FHALF + 32 + g * 8);

#pragma unroll
  for (int w = 0; w < 2; ++w) {
    const __hip_bfloat16* wb = wcb + w * 4096 + (dt * 16 + lo) * 64;
    bf16x8 wh0 = *reinterpret_cast<const bf16x8*>(wb + g * 8);
    bf16x8 wh1 = *reinterpret_cast<const bf16x8*>(wb + 32 + g * 8);
    bf16x8 wl0 = *reinterpret_cast<const bf16x8*>(wb + 8192 + g * 8);
    bf16x8 wl1 = *reinterpret_cast<const bf16x8*>(wb + 8192 + 32 + g * 8);
    float bv = cn[(w ? BT22_C : BT11_C) + dt * 16 + lo];
    f32x4 acc = {bv, bv, bv, bv};
    acc = __builtin_amdgcn_mfma_f32_16x16x32_bf16(ah0, wh0, acc, 0, 0, 0);
    acc = __builtin_amdgcn_mfma_f32_16x16x32_bf16(ah1, wh1, acc, 0, 0, 0);
    acc = __builtin_amdgcn_mfma_f32_16x16x32_bf16(al0, wh0, acc, 0, 0, 0);
    acc = __builtin_amdgcn_mfma_f32_16x16x32_bf16(al1, wh1, acc, 0, 0, 0);
    acc = __builtin_amdgcn_mfma_f32_16x16x32_bf16(ah0, wl0, acc, 0, 0, 0);
    acc = __builtin_amdgcn_mfma_f32_16x16x32_bf16(ah1, wl1, acc, 0, 0, 0);
    int sel = a ? (w ? 1 : 2) : (w ? 3 : 0);
    float* ob = fbuf + ((size_t)(sel * BB + b) * NN + ntile * 16 + g * 4) * CH + dt * 16 + lo;
    ob[0 * CH] = acc[0];
    ob[1 * CH] = acc[1];
    ob[2 * CH] = acc[2];
    ob[3 * CH] = acc[3];
  }
}

// ======================================================================
// k_knn4 (unchanged from R9, 131us): pipelined scan + packed-key merge
// networks + bitonic extraction.
// ======================================================================
__global__ __launch_bounds__(512, 4) void k_knn4(const __hip_bfloat16* __restrict__ knnb,
                                                 const float* __restrict__ knnt,
                                                 const float4* __restrict__ xyzt,
                                                 int* __restrict__ idxf) {
  __shared__ unsigned sk[16 * 8 * 33];  // 16.9 KB, reused cos -> euclid
  __shared__ int cidx[16 * 16];
  int bid = blockIdx.x;  // 2*BB*(NN/16) = 1024 : x(1) | b(1) | qt(8)
  int qt = bid & (NN / 16 - 1);
  int b = (bid >> 8) & 1;
  int x = bid >> 9;
  int w = threadIdx.x >> 6;
  int lane = threadIdx.x & 63;
  int lo = lane & 15, g = lane >> 4;
  int q0 = qt * 16;
  int j0 = w * (NN / 8);
  int ss = w * 4 + g;
  int hw = lane >> 5, sl = lane & 31;
  int qq = w * 2 + hw;  // extraction query (0..15)
  size_t qbase = (size_t)(x * BB + b) * NN;
  size_t dbase = (size_t)((1 - x) * BB + b) * NN;

  // resident query data
  const __hip_bfloat16* qb = knnb + (qbase + q0) * CH;
  bf16x8 qf0 = *reinterpret_cast<const bf16x8*>(qb + lo * CH + g * 8);
  bf16x8 qf1 = *reinterpret_cast<const bf16x8*>(qb + lo * CH + 32 + g * 8);
  const __hip_bfloat16* db = knnb + dbase * CH;
  const float4 q4 = xyzt[qbase + q0 + lo];
  const float4* dbx = xyzt + dbase;
  float tx = 2.f * q4.x, ty = 2.f * q4.y, tz = 2.f * q4.z;

  unsigned bc0[8], bc1[8], be0[8], be1[8];
#pragma unroll
  for (int k = 0; k < 8; ++k) { bc0[k] = 0u; bc1[k] = 0u; be0[k] = 0u; be1[k] = 0u; }

  auto STEP = [&](const bf16x8& A0, const bf16x8& A1, const float4& P0,
                  const float4& P1, const float4& P2, const float4& P3,
                  int rcv, unsigned (&bc)[8], unsigned (&be)[8]) {
    f32x4 acc = {0.f, 0.f, 0.f, 0.f};
    acc = __builtin_amdgcn_mfma_f32_16x16x32_bf16(A0, qf0, acc, 0, 0, 0);
    acc = __builtin_amdgcn_mfma_f32_16x16x32_bf16(A1, qf1, acc, 0, 0, 0);
    float v0 = fmaf(tx, P0.x, fmaf(ty, P0.y, fmaf(tz, P0.z, -P0.w)));
    float v1 = fmaf(tx, P1.x, fmaf(ty, P1.y, fmaf(tz, P1.z, -P1.w)));
    float v2 = fmaf(tx, P2.x, fmaf(ty, P2.y, fmaf(tz, P2.z, -P2.w)));
    float v3 = fmaf(tx, P3.x, fmaf(ty, P3.y, fmaf(tz, P3.z, -P3.w)));
    unsigned r = (unsigned)rcv;
    merge4(bc, (__float_as_uint(acc[0] + 4.0f) & 0xFFFFF000u) | r,
               (__float_as_uint(acc[1] + 4.0f) & 0xFFFFF000u) | (r - 1),
               (__float_as_uint(acc[2] + 4.0f) & 0xFFFFF000u) | (r - 2),
               (__float_as_uint(acc[3] + 4.0f) & 0xFFFFF000u) | (r - 3));
    merge4(be, (fmap(v0) & 0xFFFFF000u) | r,
               (fmap(v1) & 0xFFFFF000u) | (r - 1),
               (fmap(v2) & 0xFFFFF000u) | (r - 2),
               (fmap(v3) & 0xFFFFF000u) | (r - 3));
  };

  // ---- pipelined scan: 32 tiles, A=even / B=odd, one-tile prefetch ahead
  const __hip_bfloat16* arA = db + (size_t)(j0 + lo) * CH + g * 8;
  const __hip_bfloat16* arB = arA + 16 * CH;
  const float4* peA = dbx + j0 + g * 4;
  const float4* peB = peA + 16;
  int rc = 4095 - j0 - g * 4;

  bf16x8 aA0 = *reinterpret_cast<const bf16x8*>(arA);
  bf16x8 aA1 = *reinterpret_cast<const bf16x8*>(arA + 32);
  float4 pA0 = peA[0], pA1 = peA[1], pA2 = peA[2], pA3 = peA[3];

  for (int i = 0; i < 15; ++i) {
    bf16x8 aB0 = *reinterpret_cast<const bf16x8*>(arB);
    bf16x8 aB1 = *reinterpret_cast<const bf16x8*>(arB + 32);
    float4 pB0 = peB[0], pB1 = peB[1], pB2 = peB[2], pB3 = peB[3];
    STEP(aA0, aA1, pA0, pA1, pA2, pA3, rc, bc0, be0);
    arA += 32 * CH; peA += 32;
    aA0 = *reinterpret_cast<const bf16x8*>(arA);
    aA1 = *reinterpret_cast<const bf16x8*>(arA + 32);
    pA0 = peA[0]; pA1 = peA[1]; pA2 = peA[2]; pA3 = peA[3];
    STEP(aB0, aB1, pB0, pB1, pB2, pB3, rc - 16, bc1, be1);
    arB += 32 * CH; peB += 32;
    rc -= 32;
  }
  {
    bf16x8 aB0 = *reinterpret_cast<const bf16x8*>(arB);
    bf16x8 aB1 = *reinterpret_cast<const bf16x8*>(arB + 32);
    float4 pB0 = peB[0], pB1 = peB[1], pB2 = peB[2], pB3 = peB[3];
    STEP(aA0, aA1, pA0, pA1, pA2, pA3, rc, bc0, be0);
    STEP(aB0, aB1, pB0, pB1, pB2, pB3, rc - 16, bc1, be1);
  }
  merge88(bc0, bc1);
  merge88(be0, be1);

  // ================= cosine extraction =================
#pragma unroll
  for (int k = 0; k < 8; ++k) sk[(lo * 8 + k) * 33 + ss] = bc0[k];
  __syncthreads();
  {
    unsigned e[16];
#pragma unroll
    for (int k = 0; k < 8; ++k) e[k] = sk[(qq * 8 + k) * 33 + sl];
#pragma unroll
    for (int k = 8; k < 16; ++k) e[k] = 0u;
#pragma unroll
    for (int s = 1; s < 32; s <<= 1) {
      unsigned f[16];
#pragma unroll
      for (int k = 0; k < 16; ++k) f[k] = (unsigned)__shfl_xor((int)e[k], s, 64);
#pragma unroll
      for (int i = 0; i < 16; ++i) e[i] = umaxu(e[i], f[15 - i]);
      casu(e[0], e[8]); casu(e[1], e[9]); casu(e[2], e[10]); casu(e[3], e[11]);
      casu(e[4], e[12]); casu(e[5], e[13]); casu(e[6], e[14]); casu(e[7], e[15]);
      casu(e[0], e[4]); casu(e[1], e[5]); casu(e[2], e[6]); casu(e[3], e[7]);
      casu(e[8], e[12]); casu(e[9], e[13]); casu(e[10], e[14]); casu(e[11], e[15]);
      casu(e[0], e[2]); casu(e[1], e[3]); casu(e[4], e[6]); casu(e[5], e[7]);
      casu(e[8], e[10]); casu(e[9], e[11]); casu(e[12], e[14]); casu(e[13], e[15]);
      casu(e[0], e[1]); casu(e[2], e[3]); casu(e[4], e[5]); casu(e[6], e[7]);
      casu(e[8], e[9]); casu(e[10], e[11]); casu(e[12], e[13]); casu(e[14], e[15]);
    }
    if (sl == 0) {
#pragma unroll
      for (int k = 0; k < 16; ++k) cidx[qq * 16 + k] = 4095 - (int)(e[k] & 4095u);
    }
    int c = sl >> 1, hr = sl & 1;
    int idx = cidx[qq * 16 + c];
    const float4* qr = reinterpret_cast<const float4*>(knnt + (qbase + q0 + qq) * CH) + hr * 8;
    const float4* dr = reinterpret_cast<const float4*>(knnt + (dbase + idx) * CH) + hr * 8;
    float v = 0.f;
#pragma unroll 4
    for (int cb = 0; cb < 8; ++cb) {
      float4 qv = qr[cb], dv = dr[cb];
      v += qv.x * dv.x + qv.y * dv.y + qv.z * dv.z + qv.w * dv.w;
    }
    v += __shfl_xor(v, 1, 64);  // combine halves (bitwise identical across pair)
    int ii = idx;
#pragma unroll
    for (int k = 2; k <= 32; k <<= 1) {
#pragma unroll
      for (int j = k >> 1; j >= 1; j >>= 1) {
        float ov = __shfl_xor(v, j, 64);
        int oi = __shfl_xor(ii, j, 64);
        bool ob = (ov > v) || (ov == v && oi < ii);
        bool want = (((sl & k) == 0) == ((sl & j) == 0));
        bool take = (want == ob);
        v = take ? ov : v;
        ii = take ? oi : ii;
      }
    }
    if (sl < 16 && (sl & 1) == 0) idxf[(qbase + q0 + qq) * 16 + (sl >> 1)] = ii;
  }
  __syncthreads();

  // ================= euclid extraction =================
#pragma unroll
  for (int k = 0; k < 8; ++k) sk[(lo * 8 + k) * 33 + ss] = be0[k];
  __syncthreads();
  {
    unsigned e[16];
#pragma unroll
    for (int k = 0; k < 8; ++k) e[k] = sk[(qq * 8 + k) * 33 + sl];
#pragma unroll
    for (int k = 8; k < 16; ++k) e[k] = 0u;
#pragma unroll
    for (int s = 1; s < 32; s <<= 1) {
      unsigned f[16];
#pragma unroll
      for (int k = 0; k < 16; ++k) f[k] = (unsigned)__shfl_xor((int)e[k], s, 64);
#pragma unroll
      for (int i = 0; i < 16; ++i) e[i] = umaxu(e[i], f[15 - i]);
      casu(e[0], e[8]); casu(e[1], e[9]); casu(e[2], e[10]); casu(e[3], e[11]);
      casu(e[4], e[12]); casu(e[5], e[13]); casu(e[6], e[14]); casu(e[7], e[15]);
      casu(e[0], e[4]); casu(e[1], e[5]); casu(e[2], e[6]); casu(e[3], e[7]);
      casu(e[8], e[12]); casu(e[9], e[13]); casu(e[10], e[14]); casu(e[11], e[15]);
      casu(e[0], e[2]); casu(e[1], e[3]); casu(e[4], e[6]); casu(e[5], e[7]);
      casu(e[8], e[10]); casu(e[9], e[11]); casu(e[12], e[14]); casu(e[13], e[15]);
      casu(e[0], e[1]); casu(e[2], e[3]); casu(e[4], e[5]); casu(e[6], e[7]);
      casu(e[8], e[9]); casu(e[10], e[11]); casu(e[12], e[13]); casu(e[14], e[15]);
    }
    if (sl == 0) {
#pragma unroll
      for (int k = 0; k < 16; ++k) cidx[qq * 16 + k] = 4095 - (int)(e[k] & 4095u);
    }
    int c = sl >> 1;
    int idx = cidx[qq * 16 + c];
    const float4 qx4 = xyzt[qbase + q0 + qq];
    float4 p = xyzt[dbase + idx];
    float v = fmaf(2.f * qx4.x, p.x, fmaf(2.f * qx4.y, p.y, fmaf(2.f * qx4.z, p.z, -p.w)));
    int ii = idx;
#pragma unroll
    for (int k = 2; k <= 32; k <<= 1) {
#pragma unroll
      for (int j = k >> 1; j >= 1; j >>= 1) {
        float ov = __shfl_xor(v, j, 64);
        int oi = __shfl_xor(ii, j, 64);
        bool ob = (ov > v) || (ov == v && oi < ii);
        bool want = (((sl & k) == 0) == ((sl & j) == 0));
        bool take = (want == ob);
        v = take ? ov : v;
        ii = take ? oi : ii;
      }
    }
    if (sl < 16 && (sl & 1) == 0) idxf[(qbase + q0 + qq) * 16 + 8 + (sl >> 1)] = ii;
  }
}

// ---- fused gather + pos-conv + 2x MFMA MLP + neighbor max. One wave per query.
__global__ __launch_bounds__(256) void k_mlp(const float* __restrict__ fbuf,
                                             const float4* __restrict__ xyzt,
                                             const int* __restrict__ idxf,
                                             const float4* __restrict__ wp4,
                                             const __hip_bfloat16* __restrict__ wmb,
                                             const float* __restrict__ cn,
                                             float* __restrict__ out) {
  __shared__ __bf16 h1s[4 * 16 * 72];  // per-wave 16 rows x stride 72
  const int t = threadIdx.x;
  const int wv = t >> 6, L = t & 63;
  const int lo = L & 15, g = L >> 4;
  int bid = blockIdx.x;  // 2*BB*(NN/4) = 4096
  const int qt = bid & (NN / 4 - 1);
  const int b = (bid >> 10) & 1;
  const int x = bid >> 11;
  const int q = qt * 4 + wv;

  bf16x8 w1f[4][2], w2f[4][2];
#pragma unroll
  for (int tt = 0; tt < 4; ++tt)
#pragma unroll
    for (int kc = 0; kc < 2; ++kc) {
      int e = tt * 16 + lo, c0 = kc * 32 + g * 8;
      w1f[tt][kc] = *reinterpret_cast<const bf16x8*>(wmb + e * 64 + c0);
      w2f[tt][kc] = *reinterpret_cast<const bf16x8*>(wmb + 4096 + e * 64 + c0);
    }

  const float* pq  = fbuf + ((size_t)((x ? 2 : 0) * BB + b)) * NN * CH;
  const float* pdb = fbuf + ((size_t)((x ? 3 : 1) * BB + b)) * NN * CH;
  const float4* qx  = xyzt + (size_t)(x * BB + b) * NN;
  const float4* dbx = xyzt + (size_t)((1 - x) * BB + b) * NN;

  const int m = lo;
  int jm = idxf[(((size_t)x * BB + b) * NN + q) * 16 + m];
  jm &= (NN - 1);
  const float4 q4 = qx[q];
  const float4 p4 = dbx[jm];
  const float dx = p4.x - q4.x, dy = p4.y - q4.y, dz = p4.z - q4.z;

  const float4* g2v = reinterpret_cast<const float4*>(pdb + (size_t)jm * CH);
  const float4* pqv = reinterpret_cast<const float4*>(pq + (size_t)q * CH);
  float hv[16];
  {
    float4 t0 = g2v[g * 2], t1 = g2v[g * 2 + 1], t2 = g2v[g * 2 + 8], t3 = g2v[g * 2 + 9];
    float4 u0 = pqv[g * 2], u1 = pqv[g * 2 + 1], u2 = pqv[g * 2 + 8], u3 = pqv[g * 2 + 9];
    hv[0] = t0.x + u0.x; hv[1] = t0.y + u0.y; hv[2] = t0.z + u0.z; hv[3] = t0.w + u0.w;
    hv[4] = t1.x + u1.x; hv[5] = t1.y + u1.y; hv[6] = t1.z + u1.z; hv[7] = t1.w + u1.w;
    hv[8] = t2.x + u2.x; hv[9] = t2.y + u2.y; hv[10] = t2.z + u2.z; hv[11] = t2.w + u2.w;
    hv[12] = t3.x + u3.x; hv[13] = t3.y + u3.y; hv[14] = t3.z + u3.z; hv[15] = t3.w + u3.w;
  }

  bf16x8 a0, a1;
#pragma unroll
  for (int kc = 0; kc < 2; ++kc) {
#pragma unroll
    for (int j = 0; j < 8; ++j) {
      int c = kc * 32 + g * 8 + j;
      float4 wp = wp4[c];
      float v = hv[kc * 8 + j] + wp.x * dx + wp.y * dy + wp.z * dz + wp.w;
      v = lrelu(v);
      if (kc == 0) a0[j] = (__bf16)v; else a1[j] = (__bf16)v;
    }
  }

  __bf16* hrow = h1s + wv * 16 * 72;
#pragma unroll
  for (int tt = 0; tt < 4; ++tt) {
    float bv = cn[BM1_C + tt * 16 + lo];
    f32x4 acc = {bv, bv, bv, bv};
    acc = __builtin_amdgcn_mfma_f32_16x16x32_bf16(a0, w1f[tt][0], acc, 0, 0, 0);
    acc = __builtin_amdgcn_mfma_f32_16x16x32_bf16(a1, w1f[tt][1], acc, 0, 0, 0);
#pragma unroll
    for (int r = 0; r < 4; ++r) {
      float v = lrelu(acc[r]);
      hrow[(g * 4 + r) * 72 + tt * 16 + lo] = (__bf16)v;
    }
  }
  __syncthreads();
  bf16x8 h1a = *reinterpret_cast<const bf16x8*>(hrow + m * 72 + g * 8);
  bf16x8 h1b = *reinterpret_cast<const bf16x8*>(hrow + m * 72 + 32 + g * 8);

  size_t obase = ((size_t)(x * BB + b) * CH) * NN;
#pragma unroll
  for (int tt = 0; tt < 4; ++tt) {
    float bv = cn[BM2_C + tt * 16 + lo];
    f32x4 acc = {bv, bv, bv, bv};
    acc = __builtin_amdgcn_mfma_f32_16x16x32_bf16(h1a, w2f[tt][0], acc, 0, 0, 0);
    acc = __builtin_amdgcn_mfma_f32_16x16x32_bf16(h1b, w2f[tt][1], acc, 0, 0, 0);
    float v = fmaxf(fmaxf(lrelu(acc[0]), lrelu(acc[1])), fmaxf(lrelu(acc[2]), lrelu(acc[3])));
    v = fmaxf(v, __shfl_xor(v, 16, 64));
    v = fmaxf(v, __shfl_xor(v, 32, 64));
    if (g == 0) out[obase + (size_t)(tt * 16 + lo) * NN + q] = v;
  }
}

// workspace layout (float units) — total ~9.84M floats = 39.4 MB
#define CN_OFF 0
#define FB_OFF ((size_t)CN_TOTAL)                       // fbuf 2,097,152
#define KT_OFF (FB_OFF + (size_t)4 * BB * NN * CH)      // knnt 2,097,152
#define XZ_OFF (KT_OFF + (size_t)2 * BB * NN * CH)      // xyzt 65,536
#define WP4_OFF (XZ_OFF + (size_t)2 * BB * NN * 4)      // 256
#define WMB_OFF (WP4_OFF + 256)                         // 4096
#define IDX_OFF (WMB_OFF + 4096)                        // 262,144
#define FLAG_OFF (IDX_OFF + 262144)                     // 4
#define KNB_OFF (FLAG_OFF + 4)                          // knnb bf16 = 1,048,576 floats
#define FHL_OFF (KNB_OFF + (size_t)BB * NN * CH)        // feat hi/lo bf16 = 2,097,152 floats
#define WCB_OFF (FHL_OFF + (size_t)2 * BB * NN * CH)    // conv W hi/lo bf16 = 4,096 floats

extern "C" void kernel_launch(void* const* d_in, const int* in_sizes, int n_in,
                              void* d_out, int out_size, void* d_ws, size_t ws_size,
                              hipStream_t stream) {
  float* ws = (float*)d_ws;
  float* cn = ws + CN_OFF;
  int* flag = (int*)(ws + FLAG_OFF);

  k_detect<<<1, 64, 0, stream>>>((const unsigned short*)d_in[0], flag);
  k_ingest<<<(CN_TOTAL + 255) / 256, 256, 0, stream>>>(
      d_in[0], d_in[1], d_in[2], d_in[3], d_in[4], d_in[5], d_in[6], d_in[7],
      d_in[8], d_in[9], d_in[10], d_in[11], d_in[12], d_in[13], d_in[14], d_in[15],
      flag, cn);
  k_prep_misc<<<129, 256, 0, stream>>>(cn, (__hip_bfloat16*)(ws + WMB_OFF),
                                       (float4*)(ws + XZ_OFF), (float4*)(ws + WP4_OFF),
                                       (__hip_bfloat16*)(ws + WCB_OFF));
  k_prep_knn<<<(2 * BB * NN) / 256, 256, 0, stream>>>(cn, ws + KT_OFF,
                                                     (__hip_bfloat16*)(ws + KNB_OFF));
  k_prep_feat<<<(2 * BB * NN) / 256, 256, 0, stream>>>(cn, (__hip_bfloat16*)(ws + FHL_OFF));
  k_conv2<<<1024, 256, 0, stream>>>((const __hip_bfloat16*)(ws + FHL_OFF),
                                    (const __hip_bfloat16*)(ws + WCB_OFF), cn, ws + FB_OFF);
  k_knn4<<<2 * BB * (NN / 16), 512, 0, stream>>>(
      (const __hip_bfloat16*)(ws + KNB_OFF), ws + KT_OFF,
      (const float4*)(ws + XZ_OFF), (int*)(ws + IDX_OFF));
  k_mlp<<<2 * BB * (NN / 4), 256, 0, stream>>>(ws + FB_OFF, (const float4*)(ws + XZ_OFF),
                                               (const int*)(ws + IDX_OFF), (const float4*)(ws + WP4_OFF),
                                               (const __hip_bfloat16*)(ws + WMB_OFF), cn,
                                               (float*)d_out);
}

// Round 7
// 273.824 us; speedup vs baseline: 3.0616x; 1.0792x over previous
//
#include <hip/hip_runtime.h>
#include <hip/hip_bf16.h>

#define BB 2
#define NN 4096
#define CH 64

typedef __bf16 bf16x8 __attribute__((ext_vector_type(8)));
typedef float f32x4 __attribute__((ext_vector_type(4)));

__device__ __forceinline__ float lrelu(float v) { return fmaxf(v, 0.1f * v); }
__device__ __forceinline__ float tobf(const __hip_bfloat16& h) { return __bfloat162float(h); }

// canonical f32 input region offsets (element offsets within cn)
#define PC1_C 0
#define PC2_C 24576
#define F1_C 49152
#define F2_C 573440
#define K1_C 1097728
#define K2_C 1622016
#define WT11_C 2146304
#define BT11_C 2150400
#define WT22_C 2150464
#define BT22_C 2154560
#define WPOS_C 2154624
#define BPOS_C 2154816
#define WM1_C 2154880
#define BM1_C 2158976
#define WM2_C 2159040
#define BM2_C 2163136
#define CN_TOTAL 2163200

// fhl half offset (bf16 elements): fl mirror of fh
#define FHALF (2 * BB * NN * CH)

// ---- packed selection keys: (order-mapped f32 score, top 20 bits)<<12 | (4095-idx)
__device__ __forceinline__ unsigned fmap(float s) {
  unsigned u = __float_as_uint(s);
  return u ^ ((unsigned)((int)u >> 31) | 0x80000000u);
}

__device__ __forceinline__ unsigned umaxu(unsigned a, unsigned b) { return a > b ? a : b; }
__device__ __forceinline__ void casu(unsigned& a, unsigned& b) {
  unsigned mx = a > b ? a : b;
  unsigned mn = a > b ? b : a;
  a = mx; b = mn;
}

// bitonic-8 desc merge (input bitonic -> sorted desc)
__device__ __forceinline__ void bitonic8(unsigned bd[8]) {
  casu(bd[0], bd[4]); casu(bd[1], bd[5]); casu(bd[2], bd[6]); casu(bd[3], bd[7]);
  casu(bd[0], bd[2]); casu(bd[1], bd[3]); casu(bd[4], bd[6]); casu(bd[5], bd[7]);
  casu(bd[0], bd[1]); casu(bd[2], bd[3]); casu(bd[4], bd[5]); casu(bd[6], bd[7]);
}

// merge 4 new keys into sorted-desc-8 bd[] (branch-free)
__device__ __forceinline__ void merge4(unsigned bd[8], unsigned k0, unsigned k1,
                                       unsigned k2, unsigned k3) {
  casu(k0, k1); casu(k2, k3); casu(k0, k2); casu(k1, k3); casu(k1, k2);
  bd[4] = umaxu(bd[4], k3); bd[5] = umaxu(bd[5], k2);
  bd[6] = umaxu(bd[6], k1); bd[7] = umaxu(bd[7], k0);
  bitonic8(bd);
}

// top-8 of union of two sorted-desc-8 lists -> a[]
__device__ __forceinline__ void merge88(unsigned a[8], const unsigned b[8]) {
  a[0] = umaxu(a[0], b[7]); a[1] = umaxu(a[1], b[6]);
  a[2] = umaxu(a[2], b[5]); a[3] = umaxu(a[3], b[4]);
  a[4] = umaxu(a[4], b[3]); a[5] = umaxu(a[5], b[2]);
  a[6] = umaxu(a[6], b[1]); a[7] = umaxu(a[7], b[0]);
  bitonic8(a);
}

// cross-lane merge: a = top-8 of (a  U  partner(lane^m)'s a)
__device__ __forceinline__ void xmerge(unsigned a[8], int m) {
  unsigned t[8];
#pragma unroll
  for (int k = 0; k < 8; ++k) t[k] = (unsigned)__shfl_xor((int)a[k], m, 64);
  merge88(a, t);
}

// ---- dtype detector
__global__ void k_detect(const unsigned short* __restrict__ pc1raw, int* __restrict__ flag) {
  int lane = threadIdx.x;  // 64
  int bad = 0;
#pragma unroll
  for (int i = 0; i < 64; ++i) {
    unsigned short u = pc1raw[lane * 64 + i];
    int e = (u >> 7) & 0xFF;
    bad += (e >= 140) ? 1 : 0;  // |v| >= 2^13 or Inf/NaN
  }
#pragma unroll
  for (int s = 32; s; s >>= 1) bad += __shfl_xor(bad, s, 64);
  if (lane == 0) *flag = (bad > 16) ? 1 : 0;  // 1 = inputs are float32
}

// ---- ingest: convert all 16 inputs to canonical f32 + sanitize
__global__ __launch_bounds__(256) void k_ingest(
    const void* p0, const void* p1, const void* p2, const void* p3,
    const void* p4, const void* p5, const void* p6, const void* p7,
    const void* p8, const void* p9, const void* p10, const void* p11,
    const void* p12, const void* p13, const void* p14, const void* p15,
    const int* __restrict__ flag, float* __restrict__ dst) {
  const int cum[17] = {0, 24576, 49152, 573440, 1097728, 1622016, 2146304, 2150400,
                       2150464, 2154560, 2154624, 2154816, 2154880, 2158976, 2159040,
                       2163136, 2163200};
  size_t t = (size_t)blockIdx.x * 256 + threadIdx.x;
  if (t >= (size_t)CN_TOTAL) return;
  int seg = 0;
#pragma unroll
  for (int i = 1; i < 16; ++i) seg += (t >= (size_t)cum[i]) ? 1 : 0;
  size_t local = t - (size_t)cum[seg];
  const void* ptrs[16] = {p0, p1, p2, p3, p4, p5, p6, p7, p8, p9, p10, p11, p12, p13, p14, p15};
  const void* p = ptrs[seg];
  float v;
  if (*flag) v = ((const float*)p)[local];
  else       v = tobf(((const __hip_bfloat16*)p)[local]);
  if (!(v == v) || fabsf(v) > 1e30f) v = 0.f;  // sanitize (no-op on clean data)
  dst[t] = v;
}

// ---- fused prep (one launch): knn-normalize, feat hi/lo split, Wm->bf16,
// xyz float4, wpos, conv-W hi/lo.  Block map: [0,64) knn | [64,128) feat |
// [128,160) wm | [160,224) xyz | 224 wpos | [225,257) wcb.
__global__ __launch_bounds__(256) void k_prep_all(const float* __restrict__ cn,
                                                  float* __restrict__ knnt,
                                                  __hip_bfloat16* __restrict__ knnb,
                                                  __hip_bfloat16* __restrict__ fhl,
                                                  __hip_bfloat16* __restrict__ wmb,
                                                  float4* __restrict__ xyzt,
                                                  float4* __restrict__ wp4,
                                                  __hip_bfloat16* __restrict__ wcb) {
  int bid = blockIdx.x;
  if (bid < 64) {
    int t = bid * 256 + threadIdx.x;  // 2*BB*NN
    int n = t & (NN - 1);
    int b = (t >> 12) & 1;
    int a = t >> 13;
    const float* col = cn + (a ? K2_C : K1_C) + (size_t)b * CH * NN + n;
    float s = 0.f;
#pragma unroll
    for (int c = 0; c < CH; ++c) { float v = col[(size_t)c * NN]; s += v * v; }
    float inv = 1.0f / sqrtf(s + 1e-8f);
    size_t row = (size_t)(a * BB + b) * NN + n;
    float* o = knnt + row * CH;
    __hip_bfloat16* ob = knnb + row * CH;
#pragma unroll
    for (int c = 0; c < CH; ++c) {
      float v = col[(size_t)c * NN] * inv;
      o[c] = v;
      ob[c] = __float2bfloat16(v);
    }
  } else if (bid < 128) {
    int t = (bid - 64) * 256 + threadIdx.x;  // 2*BB*NN
    int n = t & (NN - 1);
    int b = (t >> 12) & 1;
    int a = t >> 13;
    const float* col = cn + (a ? F2_C : F1_C) + (size_t)b * CH * NN + n;
    __hip_bfloat16* oh = fhl + ((size_t)(a * BB + b) * NN + n) * CH;
    __hip_bfloat16* ol = oh + FHALF;
#pragma unroll
    for (int c = 0; c < CH; ++c) {
      float v = col[(size_t)c * NN];
      __hip_bfloat16 hi = __float2bfloat16(v);
      oh[c] = hi;
      ol[c] = __float2bfloat16(v - tobf(hi));
    }
  } else if (bid < 160) {
    int t = (bid - 128) * 256 + threadIdx.x;  // 8192
    float v = (t < 4096) ? cn[WM1_C + t] : cn[WM2_C + (t - 4096)];
    wmb[t] = __float2bfloat16(v);
  } else if (bid < 224) {
    int t = (bid - 160) * 256 + threadIdx.x;  // 2*BB*NN
    int n = t & (NN - 1);
    int b = (t >> 12) & 1;
    int a = t >> 13;
    const float* p = cn + (a ? PC2_C : PC1_C) + (size_t)b * 3 * NN + n;
    float x = p[0], y = p[NN], z = p[2 * NN];
    xyzt[(size_t)(a * BB + b) * NN + n] = make_float4(x, y, z, x * x + y * y + z * z);
  } else if (bid == 224) {
    int c = threadIdx.x;
    if (c < 64)
      wp4[c] = make_float4(cn[WPOS_C + 3 * c], cn[WPOS_C + 3 * c + 1],
                           cn[WPOS_C + 3 * c + 2], cn[BPOS_C + c]);
  } else {
    // conv weight hi/lo split: wcb[w][d*64+c] hi at [0,8192), lo at [8192,16384)
    int t = (bid - 225) * 256 + threadIdx.x;  // 8192 = 2 W x 4096
    int w = t >> 12, e = t & 4095;
    float v = cn[(w ? WT22_C : WT11_C) + e];
    __hip_bfloat16 hi = __float2bfloat16(v);
    __hip_bfloat16 lo = __float2bfloat16(v - tobf(hi));
    wcb[w * 4096 + e] = hi;
    wcb[8192 + w * 4096 + e] = lo;
  }
}

// ---- 1x1 convs on matrix pipe (bf16 hi/lo split, error ~3e-5)
__global__ __launch_bounds__(256) void k_conv2(const __hip_bfloat16* __restrict__ fhl,
                                               const __hip_bfloat16* __restrict__ wcb,
                                               const float* __restrict__ cn,
                                               float* __restrict__ fbuf) {
  int bid = blockIdx.x;  // 1024: ntile(8b) | b(1) | a(1)
  int ntile = bid & 255;
  int b = (bid >> 8) & 1;
  int a = bid >> 9;
  int t = threadIdx.x;
  int dt = t >> 6;  // wave = d-tile (0..3)
  int lane = t & 63;
  int lo = lane & 15, g = lane >> 4;

  const __hip_bfloat16* fb = fhl + ((size_t)(a * BB + b) * NN + ntile * 16 + lo) * CH;
  bf16x8 ah0 = *reinterpret_cast<const bf16x8*>(fb + g * 8);
  bf16x8 ah1 = *reinterpret_cast<const bf16x8*>(fb + 32 + g * 8);
  bf16x8 al0 = *reinterpret_cast<const bf16x8*>(fb + FHALF + g * 8);
  bf16x8 al1 = *reinterpret_cast<const bf16x8*>(fb + FHALF + 32 + g * 8);

#pragma unroll
  for (int w = 0; w < 2; ++w) {
    const __hip_bfloat16* wb = wcb + w * 4096 + (dt * 16 + lo) * 64;
    bf16x8 wh0 = *reinterpret_cast<const bf16x8*>(wb + g * 8);
    bf16x8 wh1 = *reinterpret_cast<const bf16x8*>(wb + 32 + g * 8);
    bf16x8 wl0 = *reinterpret_cast<const bf16x8*>(wb + 8192 + g * 8);
    bf16x8 wl1 = *reinterpret_cast<const bf16x8*>(wb + 8192 + 32 + g * 8);
    float bv = cn[(w ? BT22_C : BT11_C) + dt * 16 + lo];
    f32x4 acc = {bv, bv, bv, bv};
    acc = __builtin_amdgcn_mfma_f32_16x16x32_bf16(ah0, wh0, acc, 0, 0, 0);
    acc = __builtin_amdgcn_mfma_f32_16x16x32_bf16(ah1, wh1, acc, 0, 0, 0);
    acc = __builtin_amdgcn_mfma_f32_16x16x32_bf16(al0, wh0, acc, 0, 0, 0);
    acc = __builtin_amdgcn_mfma_f32_16x16x32_bf16(al1, wh1, acc, 0, 0, 0);
    acc = __builtin_amdgcn_mfma_f32_16x16x32_bf16(ah0, wl0, acc, 0, 0, 0);
    acc = __builtin_amdgcn_mfma_f32_16x16x32_bf16(ah1, wl1, acc, 0, 0, 0);
    int sel = a ? (w ? 1 : 2) : (w ? 3 : 0);
    float* ob = fbuf + ((size_t)(sel * BB + b) * NN + ntile * 16 + g * 4) * CH + dt * 16 + lo;
    ob[0 * CH] = acc[0];
    ob[1 * CH] = acc[1];
    ob[2 * CH] = acc[2];
    ob[3 * CH] = acc[3];
  }
}

// ======================================================================
// R11 k_knn5: extraction is serial-latency bound (3 structure variants of
// the scan all land 130-140us; VALUBusy ~47%). Cut the serial chains:
// after the scan, cross-merge the 4 lane-groups' top-8 IN REGISTERS
// (shfl_xor 16/32 + merge88, once) -> 8 substreams instead of 32.
// Extraction butterfly: 3 stages instead of 5; LDS dump traffic /4.
// ======================================================================
__global__ __launch_bounds__(512, 4) void k_knn5(const __hip_bfloat16* __restrict__ knnb,
                                                 const float* __restrict__ knnt,
                                                 const float4* __restrict__ xyzt,
                                                 int* __restrict__ idxf) {
  __shared__ unsigned sk[16 * 8 * 9];  // [q*8+k][9 wave slots] 4.6 KB
  __shared__ int cidx[16 * 16];
  int bid = blockIdx.x;  // 2*BB*(NN/16) = 1024 : x(1) | b(1) | qt(8)
  int qt = bid & (NN / 16 - 1);
  int b = (bid >> 8) & 1;
  int x = bid >> 9;
  int w = threadIdx.x >> 6;
  int lane = threadIdx.x & 63;
  int lo = lane & 15, g = lane >> 4;
  int q0 = qt * 16;
  int j0 = w * (NN / 8);
  int hw = lane >> 5, sl = lane & 31;
  int qq = w * 2 + hw;  // extraction query (0..15)
  size_t qbase = (size_t)(x * BB + b) * NN;
  size_t dbase = (size_t)((1 - x) * BB + b) * NN;

  // resident query data
  const __hip_bfloat16* qb = knnb + (qbase + q0) * CH;
  bf16x8 qf0 = *reinterpret_cast<const bf16x8*>(qb + lo * CH + g * 8);
  bf16x8 qf1 = *reinterpret_cast<const bf16x8*>(qb + lo * CH + 32 + g * 8);
  const __hip_bfloat16* db = knnb + dbase * CH;
  const float4 q4 = xyzt[qbase + q0 + lo];
  const float4* dbx = xyzt + dbase;
  float tx = 2.f * q4.x, ty = 2.f * q4.y, tz = 2.f * q4.z;

  unsigned bc0[8], bc1[8], be0[8], be1[8];
#pragma unroll
  for (int k = 0; k < 8; ++k) { bc0[k] = 0u; bc1[k] = 0u; be0[k] = 0u; be1[k] = 0u; }

  auto STEP = [&](const bf16x8& A0, const bf16x8& A1, const float4& P0,
                  const float4& P1, const float4& P2, const float4& P3,
                  int rcv, unsigned (&bc)[8], unsigned (&be)[8]) {
    f32x4 acc = {0.f, 0.f, 0.f, 0.f};
    acc = __builtin_amdgcn_mfma_f32_16x16x32_bf16(A0, qf0, acc, 0, 0, 0);
    acc = __builtin_amdgcn_mfma_f32_16x16x32_bf16(A1, qf1, acc, 0, 0, 0);
    float v0 = fmaf(tx, P0.x, fmaf(ty, P0.y, fmaf(tz, P0.z, -P0.w)));
    float v1 = fmaf(tx, P1.x, fmaf(ty, P1.y, fmaf(tz, P1.z, -P1.w)));
    float v2 = fmaf(tx, P2.x, fmaf(ty, P2.y, fmaf(tz, P2.z, -P2.w)));
    float v3 = fmaf(tx, P3.x, fmaf(ty, P3.y, fmaf(tz, P3.z, -P3.w)));
    unsigned r = (unsigned)rcv;
    merge4(bc, (__float_as_uint(acc[0] + 4.0f) & 0xFFFFF000u) | r,
               (__float_as_uint(acc[1] + 4.0f) & 0xFFFFF000u) | (r - 1),
               (__float_as_uint(acc[2] + 4.0f) & 0xFFFFF000u) | (r - 2),
               (__float_as_uint(acc[3] + 4.0f) & 0xFFFFF000u) | (r - 3));
    merge4(be, (fmap(v0) & 0xFFFFF000u) | r,
               (fmap(v1) & 0xFFFFF000u) | (r - 1),
               (fmap(v2) & 0xFFFFF000u) | (r - 2),
               (fmap(v3) & 0xFFFFF000u) | (r - 3));
  };

  // ---- pipelined scan: 32 tiles, A=even / B=odd, one-tile prefetch ahead
  const __hip_bfloat16* arA = db + (size_t)(j0 + lo) * CH + g * 8;
  const __hip_bfloat16* arB = arA + 16 * CH;
  const float4* peA = dbx + j0 + g * 4;
  const float4* peB = peA + 16;
  int rc = 4095 - j0 - g * 4;

  bf16x8 aA0 = *reinterpret_cast<const bf16x8*>(arA);
  bf16x8 aA1 = *reinterpret_cast<const bf16x8*>(arA + 32);
  float4 pA0 = peA[0], pA1 = peA[1], pA2 = peA[2], pA3 = peA[3];

  for (int i = 0; i < 15; ++i) {
    bf16x8 aB0 = *reinterpret_cast<const bf16x8*>(arB);
    bf16x8 aB1 = *reinterpret_cast<const bf16x8*>(arB + 32);
    float4 pB0 = peB[0], pB1 = peB[1], pB2 = peB[2], pB3 = peB[3];
    STEP(aA0, aA1, pA0, pA1, pA2, pA3, rc, bc0, be0);
    arA += 32 * CH; peA += 32;
    aA0 = *reinterpret_cast<const bf16x8*>(arA);
    aA1 = *reinterpret_cast<const bf16x8*>(arA + 32);
    pA0 = peA[0]; pA1 = peA[1]; pA2 = peA[2]; pA3 = peA[3];
    STEP(aB0, aB1, pB0, pB1, pB2, pB3, rc - 16, bc1, be1);
    arB += 32 * CH; peB += 32;
    rc -= 32;
  }
  {
    bf16x8 aB0 = *reinterpret_cast<const bf16x8*>(arB);
    bf16x8 aB1 = *reinterpret_cast<const bf16x8*>(arB + 32);
    float4 pB0 = peB[0], pB1 = peB[1], pB2 = peB[2], pB3 = peB[3];
    STEP(aA0, aA1, pA0, pA1, pA2, pA3, rc, bc0, be0);
    STEP(aB0, aB1, pB0, pB1, pB2, pB3, rc - 16, bc1, be1);
  }
  merge88(bc0, bc1);
  merge88(be0, be1);
  // cross-group register merge: 32 substreams -> 8 (one per wave, per query)
  xmerge(bc0, 16); xmerge(bc0, 32);
  xmerge(be0, 16); xmerge(be0, 32);

  // ================= cosine extraction =================
  if (g == 0) {
#pragma unroll
    for (int k = 0; k < 8; ++k) sk[(lo * 8 + k) * 9 + w] = bc0[k];
  }
  __syncthreads();
  {
    unsigned e[16];
#pragma unroll
    for (int k = 0; k < 8; ++k) e[k] = sk[(qq * 8 + k) * 9 + (sl & 7)];
#pragma unroll
    for (int k = 8; k < 16; ++k) e[k] = 0u;
#pragma unroll
    for (int s = 1; s < 8; s <<= 1) {
      unsigned f[16];
#pragma unroll
      for (int k = 0; k < 16; ++k) f[k] = (unsigned)__shfl_xor((int)e[k], s, 64);
#pragma unroll
      for (int i = 0; i < 16; ++i) e[i] = umaxu(e[i], f[15 - i]);
      casu(e[0], e[8]); casu(e[1], e[9]); casu(e[2], e[10]); casu(e[3], e[11]);
      casu(e[4], e[12]); casu(e[5], e[13]); casu(e[6], e[14]); casu(e[7], e[15]);
      casu(e[0], e[4]); casu(e[1], e[5]); casu(e[2], e[6]); casu(e[3], e[7]);
      casu(e[8], e[12]); casu(e[9], e[13]); casu(e[10], e[14]); casu(e[11], e[15]);
      casu(e[0], e[2]); casu(e[1], e[3]); casu(e[4], e[6]); casu(e[5], e[7]);
      casu(e[8], e[10]); casu(e[9], e[11]); casu(e[12], e[14]); casu(e[13], e[15]);
      casu(e[0], e[1]); casu(e[2], e[3]); casu(e[4], e[5]); casu(e[6], e[7]);
      casu(e[8], e[9]); casu(e[10], e[11]); casu(e[12], e[13]); casu(e[14], e[15]);
    }
    if (sl == 0) {
#pragma unroll
      for (int k = 0; k < 16; ++k) cidx[qq * 16 + k] = 4095 - (int)(e[k] & 4095u);
    }
    int c = sl >> 1, hr = sl & 1;
    int idx = cidx[qq * 16 + c];
    const float4* qr = reinterpret_cast<const float4*>(knnt + (qbase + q0 + qq) * CH) + hr * 8;
    const float4* dr = reinterpret_cast<const float4*>(knnt + (dbase + idx) * CH) + hr * 8;
    float v = 0.f;
#pragma unroll 4
    for (int cb = 0; cb < 8; ++cb) {
      float4 qv = qr[cb], dv = dr[cb];
      v += qv.x * dv.x + qv.y * dv.y + qv.z * dv.z + qv.w * dv.w;
    }
    v += __shfl_xor(v, 1, 64);  // combine halves (bitwise identical across pair)
    int ii = idx;
#pragma unroll
    for (int k = 2; k <= 32; k <<= 1) {
#pragma unroll
      for (int j = k >> 1; j >= 1; j >>= 1) {
        float ov = __shfl_xor(v, j, 64);
        int oi = __shfl_xor(ii, j, 64);
        bool ob = (ov > v) || (ov == v && oi < ii);
        bool want = (((sl & k) == 0) == ((sl & j) == 0));
        bool take = (want == ob);
        v = take ? ov : v;
        ii = take ? oi : ii;
      }
    }
    if (sl < 16 && (sl & 1) == 0) idxf[(qbase + q0 + qq) * 16 + (sl >> 1)] = ii;
  }
  __syncthreads();

  // ================= euclid extraction =================
  if (g == 0) {
#pragma unroll
    for (int k = 0; k < 8; ++k) sk[(lo * 8 + k) * 9 + w] = be0[k];
  }
  __syncthreads();
  {
    unsigned e[16];
#pragma unroll
    for (int k = 0; k < 8; ++k) e[k] = sk[(qq * 8 + k) * 9 + (sl & 7)];
#pragma unroll
    for (int k = 8; k < 16; ++k) e[k] = 0u;
#pragma unroll
    for (int s = 1; s < 8; s <<= 1) {
      unsigned f[16];
#pragma unroll
      for (int k = 0; k < 16; ++k) f[k] = (unsigned)__shfl_xor((int)e[k], s, 64);
#pragma unroll
      for (int i = 0; i < 16; ++i) e[i] = umaxu(e[i], f[15 - i]);
      casu(e[0], e[8]); casu(e[1], e[9]); casu(e[2], e[10]); casu(e[3], e[11]);
      casu(e[4], e[12]); casu(e[5], e[13]); casu(e[6], e[14]); casu(e[7], e[15]);
      casu(e[0], e[4]); casu(e[1], e[5]); casu(e[2], e[6]); casu(e[3], e[7]);
      casu(e[8], e[12]); casu(e[9], e[13]); casu(e[10], e[14]); casu(e[11], e[15]);
      casu(e[0], e[2]); casu(e[1], e[3]); casu(e[4], e[6]); casu(e[5], e[7]);
      casu(e[8], e[10]); casu(e[9], e[11]); casu(e[12], e[14]); casu(e[13], e[15]);
      casu(e[0], e[1]); casu(e[2], e[3]); casu(e[4], e[5]); casu(e[6], e[7]);
      casu(e[8], e[9]); casu(e[10], e[11]); casu(e[12], e[13]); casu(e[14], e[15]);
    }
    if (sl == 0) {
#pragma unroll
      for (int k = 0; k < 16; ++k) cidx[qq * 16 + k] = 4095 - (int)(e[k] & 4095u);
    }
    int c = sl >> 1;
    int idx = cidx[qq * 16 + c];
    const float4 qx4 = xyzt[qbase + q0 + qq];
    float4 p = xyzt[dbase + idx];
    float v = fmaf(2.f * qx4.x, p.x, fmaf(2.f * qx4.y, p.y, fmaf(2.f * qx4.z, p.z, -p.w)));
    int ii = idx;
#pragma unroll
    for (int k = 2; k <= 32; k <<= 1) {
#pragma unroll
      for (int j = k >> 1; j >= 1; j >>= 1) {
        float ov = __shfl_xor(v, j, 64);
        int oi = __shfl_xor(ii, j, 64);
        bool ob = (ov > v) || (ov == v && oi < ii);
        bool want = (((sl & k) == 0) == ((sl & j) == 0));
        bool take = (want == ob);
        v = take ? ov : v;
        ii = take ? oi : ii;
      }
    }
    if (sl < 16 && (sl & 1) == 0) idxf[(qbase + q0 + qq) * 16 + 8 + (sl >> 1)] = ii;
  }
}

// ---- fused gather + pos-conv + 2x MFMA MLP + neighbor max. One wave per query.
__global__ __launch_bounds__(256) void k_mlp(const float* __restrict__ fbuf,
                                             const float4* __restrict__ xyzt,
                                             const int* __restrict__ idxf,
                                             const float4* __restrict__ wp4,
                                             const __hip_bfloat16* __restrict__ wmb,
                                             const float* __restrict__ cn,
                                             float* __restrict__ out) {
  __shared__ __bf16 h1s[4 * 16 * 72];  // per-wave 16 rows x stride 72
  const int t = threadIdx.x;
  const int wv = t >> 6, L = t & 63;
  const int lo = L & 15, g = L >> 4;
  int bid = blockIdx.x;  // 2*BB*(NN/4) = 4096
  const int qt = bid & (NN / 4 - 1);
  const int b = (bid >> 10) & 1;
  const int x = bid >> 11;
  const int q = qt * 4 + wv;

  bf16x8 w1f[4][2], w2f[4][2];
#pragma unroll
  for (int tt = 0; tt < 4; ++tt)
#pragma unroll
    for (int kc = 0; kc < 2; ++kc) {
      int e = tt * 16 + lo, c0 = kc * 32 + g * 8;
      w1f[tt][kc] = *reinterpret_cast<const bf16x8*>(wmb + e * 64 + c0);
      w2f[tt][kc] = *reinterpret_cast<const bf16x8*>(wmb + 4096 + e * 64 + c0);
    }

  const float* pq  = fbuf + ((size_t)((x ? 2 : 0) * BB + b)) * NN * CH;
  const float* pdb = fbuf + ((size_t)((x ? 3 : 1) * BB + b)) * NN * CH;
  const float4* qx  = xyzt + (size_t)(x * BB + b) * NN;
  const float4* dbx = xyzt + (size_t)((1 - x) * BB + b) * NN;

  const int m = lo;
  int jm = idxf[(((size_t)x * BB + b) * NN + q) * 16 + m];
  jm &= (NN - 1);
  const float4 q4 = qx[q];
  const float4 p4 = dbx[jm];
  const float dx = p4.x - q4.x, dy = p4.y - q4.y, dz = p4.z - q4.z;

  const float4* g2v = reinterpret_cast<const float4*>(pdb + (size_t)jm * CH);
  const float4* pqv = reinterpret_cast<const float4*>(pq + (size_t)q * CH);
  float hv[16];
  {
    float4 t0 = g2v[g * 2], t1 = g2v[g * 2 + 1], t2 = g2v[g * 2 + 8], t3 = g2v[g * 2 + 9];
    float4 u0 = pqv[g * 2], u1 = pqv[g * 2 + 1], u2 = pqv[g * 2 + 8], u3 = pqv[g * 2 + 9];
    hv[0] = t0.x + u0.x; hv[1] = t0.y + u0.y; hv[2] = t0.z + u0.z; hv[3] = t0.w + u0.w;
    hv[4] = t1.x + u1.x; hv[5] = t1.y + u1.y; hv[6] = t1.z + u1.z; hv[7] = t1.w + u1.w;
    hv[8] = t2.x + u2.x; hv[9] = t2.y + u2.y; hv[10] = t2.z + u2.z; hv[11] = t2.w + u2.w;
    hv[12] = t3.x + u3.x; hv[13] = t3.y + u3.y; hv[14] = t3.z + u3.z; hv[15] = t3.w + u3.w;
  }

  bf16x8 a0, a1;
#pragma unroll
  for (int kc = 0; kc < 2; ++kc) {
#pragma unroll
    for (int j = 0; j < 8; ++j) {
      int c = kc * 32 + g * 8 + j;
      float4 wp = wp4[c];
      float v = hv[kc * 8 + j] + wp.x * dx + wp.y * dy + wp.z * dz + wp.w;
      v = lrelu(v);
      if (kc == 0) a0[j] = (__bf16)v; else a1[j] = (__bf16)v;
    }
  }

  __bf16* hrow = h1s + wv * 16 * 72;
#pragma unroll
  for (int tt = 0; tt < 4; ++tt) {
    float bv = cn[BM1_C + tt * 16 + lo];
    f32x4 acc = {bv, bv, bv, bv};
    acc = __builtin_amdgcn_mfma_f32_16x16x32_bf16(a0, w1f[tt][0], acc, 0, 0, 0);
    acc = __builtin_amdgcn_mfma_f32_16x16x32_bf16(a1, w1f[tt][1], acc, 0, 0, 0);
#pragma unroll
    for (int r = 0; r < 4; ++r) {
      float v = lrelu(acc[r]);
      hrow[(g * 4 + r) * 72 + tt * 16 + lo] = (__bf16)v;
    }
  }
  __syncthreads();
  bf16x8 h1a = *reinterpret_cast<const bf16x8*>(hrow + m * 72 + g * 8);
  bf16x8 h1b = *reinterpret_cast<const bf16x8*>(hrow + m * 72 + 32 + g * 8);

  size_t obase = ((size_t)(x * BB + b) * CH) * NN;
#pragma unroll
  for (int tt = 0; tt < 4; ++tt) {
    float bv = cn[BM2_C + tt * 16 + lo];
    f32x4 acc = {bv, bv, bv, bv};
    acc = __builtin_amdgcn_mfma_f32_16x16x32_bf16(h1a, w2f[tt][0], acc, 0, 0, 0);
    acc = __builtin_amdgcn_mfma_f32_16x16x32_bf16(h1b, w2f[tt][1], acc, 0, 0, 0);
    float v = fmaxf(fmaxf(lrelu(acc[0]), lrelu(acc[1])), fmaxf(lrelu(acc[2]), lrelu(acc[3])));
    v = fmaxf(v, __shfl_xor(v, 16, 64));
    v = fmaxf(v, __shfl_xor(v, 32, 64));
    if (g == 0) out[obase + (size_t)(tt * 16 + lo) * NN + q] = v;
  }
}

// workspace layout (float units)
#define CN_OFF 0
#define FB_OFF ((size_t)CN_TOTAL)
#define KT_OFF (FB_OFF + (size_t)4 * BB * NN * CH)
#define XZ_OFF (KT_OFF + (size_t)2 * BB * NN * CH)
#define WP4_OFF (XZ_OFF + (size_t)2 * BB * NN * 4)
#define WMB_OFF (WP4_OFF + 256)
#define IDX_OFF (WMB_OFF + 4096)
#define FLAG_OFF (IDX_OFF + 262144)
#define KNB_OFF (FLAG_OFF + 4)
#define FHL_OFF (KNB_OFF + (size_t)BB * NN * CH)
#define WCB_OFF (FHL_OFF + (size_t)2 * BB * NN * CH)

extern "C" void kernel_launch(void* const* d_in, const int* in_sizes, int n_in,
                              void* d_out, int out_size, void* d_ws, size_t ws_size,
                              hipStream_t stream) {
  float* ws = (float*)d_ws;
  float* cn = ws + CN_OFF;
  int* flag = (int*)(ws + FLAG_OFF);

  k_detect<<<1, 64, 0, stream>>>((const unsigned short*)d_in[0], flag);
  k_ingest<<<(CN_TOTAL + 255) / 256, 256, 0, stream>>>(
      d_in[0], d_in[1], d_in[2], d_in[3], d_in[4], d_in[5], d_in[6], d_in[7],
      d_in[8], d_in[9], d_in[10], d_in[11], d_in[12], d_in[13], d_in[14], d_in[15],
      flag, cn);
  k_prep_all<<<257, 256, 0, stream>>>(cn, ws + KT_OFF, (__hip_bfloat16*)(ws + KNB_OFF),
                                      (__hip_bfloat16*)(ws + FHL_OFF),
                                      (__hip_bfloat16*)(ws + WMB_OFF),
                                      (float4*)(ws + XZ_OFF), (float4*)(ws + WP4_OFF),
                                      (__hip_bfloat16*)(ws + WCB_OFF));
  k_conv2<<<1024, 256, 0, stream>>>((const __hip_bfloat16*)(ws + FHL_OFF),
                                    (const __hip_bfloat16*)(ws + WCB_OFF), cn, ws + FB_OFF);
  k_knn5<<<2 * BB * (NN / 16), 512, 0, stream>>>(
      (const __hip_bfloat16*)(ws + KNB_OFF), ws + KT_OFF,
      (const float4*)(ws + XZ_OFF), (int*)(ws + IDX_OFF));
  k_mlp<<<2 * BB * (NN / 4), 256, 0, stream>>>(ws + FB_OFF, (const float4*)(ws + XZ_OFF),
                                               (const int*)(ws + IDX_OFF), (const float4*)(ws + WP4_OFF),
                                               (const __hip_bfloat16*)(ws + WMB_OFF), cn,
                                               (float*)d_out);
}